// Round 9
// baseline (357.259 us; speedup 1.0000x reference)
//
#include <hip/hip_runtime.h>
#include <math.h>

#define NTOK 1024
#define DIMM 512
#define NH 8
#define HD 64
#define BCB 16
#define BSB 16
#define KSEL 8
#define WWIN 256
#define CBLK 64
#define SCALE 0.125f
#define EPSV 1e-6f
#define NEGV -1e30f

typedef short bf16x8 __attribute__((ext_vector_type(8)));
typedef float f32x4 __attribute__((ext_vector_type(4)));

__device__ inline ushort f2b(float f) {
  union { float f; unsigned int u; } c; c.f = f;
  unsigned int u = c.u;
  return (ushort)((u + 0x7FFFu + ((u >> 16) & 1u)) >> 16);
}
__device__ inline float b2f(ushort h) {
  union { unsigned int u; float f; } c; c.u = ((unsigned int)h) << 16;
  return c.f;
}

__device__ inline float wred_max(float v) {
#pragma unroll
  for (int off = 1; off < 64; off <<= 1) v = fmaxf(v, __shfl_xor(v, off));
  return v;
}
__device__ inline float wred_sum(float v) {
#pragma unroll
  for (int off = 1; off < 64; off <<= 1) v += __shfl_xor(v, off);
  return v;
}

// ---------- residual mix + rmsnorm ----------
__global__ void __launch_bounds__(256)
k_resid_rms(const float* __restrict__ x, const float* __restrict__ x0,
            const float* __restrict__ lam, float* __restrict__ xr,
            float* __restrict__ xn) {
  int row = blockIdx.x, tid = threadIdx.x;
  float l0 = lam[0], l1 = lam[1];
  size_t b = (size_t)row * DIMM;
  float a0 = l0 * x[b + tid]       + l1 * x0[b + tid];
  float a1 = l0 * x[b + tid + 256] + l1 * x0[b + tid + 256];
  xr[b + tid] = a0; xr[b + tid + 256] = a1;
  float ss = a0 * a0 + a1 * a1;
  __shared__ float sm[8];
  for (int o = 32; o > 0; o >>= 1) ss += __shfl_down(ss, o);
  int lane = tid & 63, wid = tid >> 6;
  if (lane == 0) sm[wid] = ss;
  __syncthreads();
  if (tid == 0) {
    float s = sm[0] + sm[1] + sm[2] + sm[3];
    sm[0] = rsqrtf(s / (float)DIMM + EPSV);
  }
  __syncthreads();
  float r = sm[0];
  xn[b + tid] = a0 * r; xn[b + tid + 256] = a1 * r;
}

// ---------- rmsnorm -> bf16 output ----------
__global__ void __launch_bounds__(256)
k_rms_bf(const float* __restrict__ xin, ushort* __restrict__ y) {
  int row = blockIdx.x, tid = threadIdx.x;
  size_t b = (size_t)row * DIMM;
  float a0 = xin[b + tid], a1 = xin[b + tid + 256];
  float ss = a0 * a0 + a1 * a1;
  __shared__ float sm[8];
  for (int o = 32; o > 0; o >>= 1) ss += __shfl_down(ss, o);
  int lane = tid & 63, wid = tid >> 6;
  if (lane == 0) sm[wid] = ss;
  __syncthreads();
  if (tid == 0) {
    float s = sm[0] + sm[1] + sm[2] + sm[3];
    sm[0] = rsqrtf(s / (float)DIMM + EPSV);
  }
  __syncthreads();
  float r = sm[0];
  y[b + tid] = f2b(a0 * r); y[b + tid + 256] = f2b(a1 * r);
}

// ---------- consolidated weight transposes (f32 K×N -> bf16 hi/lo N×K) ----------
struct WtrDesc { const float* src; ushort* dh; ushort* dl; int K; int Nsrc; int Npad; };
struct WtrPack { WtrDesc d[9]; int cum[9]; };

__global__ void __launch_bounds__(256)
k_wtr_all(WtrPack pk) {
  int gb = blockIdx.x;
  int e = 0;
  while (gb >= pk.cum[e]) e++;
  int start = e ? pk.cum[e - 1] : 0;
  WtrDesc dd = pk.d[e];
  int local = gb - start;
  int XT = dd.Npad >> 5;
  int bx = local % XT, by = local / XT;
  __shared__ float t[32][33];
  int n0 = bx * 32, k0 = by * 32;
  int tx = threadIdx.x, ty = threadIdx.y;  // 32 x 8
#pragma unroll
  for (int i = 0; i < 32; i += 8)
    t[ty + i][tx] = (n0 + tx < dd.Nsrc)
        ? dd.src[(size_t)(k0 + ty + i) * dd.Nsrc + n0 + tx] : 0.f;
  __syncthreads();
#pragma unroll
  for (int i = 0; i < 32; i += 8) {
    float vv = t[tx][ty + i];
    ushort h = f2b(vv);
    size_t di = (size_t)(n0 + ty + i) * dd.K + k0 + tx;
    dd.dh[di] = h;
    if (dd.dl) dd.dl[di] = f2b(vv - b2f(h));
  }
}

// ---------- 128x128-tile bf16 MFMA GEMM (A bf16 in memory) ----------
// epi 1: relu^2 -> bf16 store ; epi 2: f32 store + Res
__global__ void __launch_bounds__(256)
k_gemm_mlp(const ushort* __restrict__ A, const ushort* __restrict__ BT,
           const float* __restrict__ Res, void* __restrict__ Co,
           int Kd, int Nd, int epi) {
  __shared__ ushort As[128 * 40];
  __shared__ ushort Bs[128 * 40];
  int tid = threadIdx.x;
  int lane = tid & 63, w = tid >> 6;
  int rb = blockIdx.y * 128, cb = blockIdx.x * 128;
  int wm = (w >> 1) * 64, wn = (w & 1) * 64;
  int quad = lane >> 4, l15 = lane & 15;
  int srow = tid >> 1, scol = (tid & 1) * 16;

  f32x4 acc[4][4];
#pragma unroll
  for (int i = 0; i < 4; i++)
#pragma unroll
    for (int j = 0; j < 4; j++) acc[i][j] = (f32x4){0.f, 0.f, 0.f, 0.f};

  const ushort* ap = A  + (size_t)(rb + srow) * Kd + scol;
  const ushort* bp = BT + (size_t)(cb + srow) * Kd + scol;
  ushort* aw = &As[srow * 40 + scol];
  ushort* bw = &Bs[srow * 40 + scol];

  for (int k0 = 0; k0 < Kd; k0 += 32) {
    *(int4*)aw       = *(const int4*)(ap + k0);
    *(int4*)(aw + 8) = *(const int4*)(ap + k0 + 8);
    *(int4*)bw       = *(const int4*)(bp + k0);
    *(int4*)(bw + 8) = *(const int4*)(bp + k0 + 8);
    __syncthreads();
    bf16x8 af[4], bfr[4];
#pragma unroll
    for (int t = 0; t < 4; t++) {
      af[t]  = *(const bf16x8*)&As[(wm + t * 16 + l15) * 40 + quad * 8];
      bfr[t] = *(const bf16x8*)&Bs[(wn + t * 16 + l15) * 40 + quad * 8];
    }
#pragma unroll
    for (int i = 0; i < 4; i++)
#pragma unroll
      for (int j = 0; j < 4; j++)
        acc[i][j] = __builtin_amdgcn_mfma_f32_16x16x32_bf16(af[i], bfr[j],
                                                            acc[i][j], 0, 0, 0);
    __syncthreads();
  }

#pragma unroll
  for (int i = 0; i < 4; i++) {
#pragma unroll
    for (int j = 0; j < 4; j++) {
      int col = cb + wn + j * 16 + l15;
#pragma unroll
      for (int r = 0; r < 4; r++) {
        int row = rb + wm + i * 16 + quad * 4 + r;
        float vv = acc[i][j][r];
        if (epi == 1) {
          float t = fmaxf(vv, 0.f);
          ((ushort*)Co)[(size_t)row * Nd + col] = f2b(t * t);
        } else {
          ((float*)Co)[(size_t)row * Nd + col] =
              vv + Res[(size_t)row * Nd + col];
        }
      }
    }
  }
}

// ---------- Wo GEMM with fused gated combine in A-staging ----------
__global__ void __launch_bounds__(256)
k_gemm_wo(const float* __restrict__ cg, const float* __restrict__ fg,
          const float* __restrict__ sg, const float* __restrict__ gates,
          const ushort* __restrict__ BT, const float* __restrict__ Res,
          float* __restrict__ Co) {
  __shared__ ushort As[64 * 40];
  __shared__ ushort Bs[64 * 40];
  int tid = threadIdx.x;
  int lane = tid & 63, wave = tid >> 6;
  int rb = blockIdx.y * 64, cb = blockIdx.x * 64;
  int wm = (wave >> 1) * 32, wn = (wave & 1) * 32;
  int q = lane >> 4, l15 = lane & 15;
  int srow = tid >> 2, scol = (tid & 3) * 8;

  f32x4 acc[2][2];
#pragma unroll
  for (int i = 0; i < 2; i++)
#pragma unroll
    for (int j = 0; j < 2; j++) acc[i][j] = (f32x4){0.f, 0.f, 0.f, 0.f};

  int row = rb + srow;
  const ushort* bp = BT + (size_t)(cb + srow) * 512 + scol;
  ushort* aw = &As[srow * 40 + scol];
  ushort* bw = &Bs[srow * 40 + scol];

  for (int k0 = 0; k0 < 512; k0 += 32) {
    int colb = k0 + scol;
    int hh = colb >> 6;
    const float* gp = gates + (size_t)row * 24 + hh * 3;
    float g0 = gp[0], g1 = gp[1], g2 = gp[2];
    size_t off = (size_t)row * 512 + colb;
    float4 c0 = *(const float4*)(cg + off), c1 = *(const float4*)(cg + off + 4);
    float4 f0 = *(const float4*)(fg + off), f1 = *(const float4*)(fg + off + 4);
    float4 s0 = *(const float4*)(sg + off), s1 = *(const float4*)(sg + off + 4);
    float va[8] = {g0 * c0.x + g1 * f0.x + g2 * s0.x,
                   g0 * c0.y + g1 * f0.y + g2 * s0.y,
                   g0 * c0.z + g1 * f0.z + g2 * s0.z,
                   g0 * c0.w + g1 * f0.w + g2 * s0.w,
                   g0 * c1.x + g1 * f1.x + g2 * s1.x,
                   g0 * c1.y + g1 * f1.y + g2 * s1.y,
                   g0 * c1.z + g1 * f1.z + g2 * s1.z,
                   g0 * c1.w + g1 * f1.w + g2 * s1.w};
    ushort h[8];
#pragma unroll
    for (int e = 0; e < 8; e++) h[e] = f2b(va[e]);
    *(int4*)aw = *(int4*)h;
    *(int4*)bw = *(const int4*)(bp + k0);
    __syncthreads();
    bf16x8 af[2], bfr[2];
#pragma unroll
    for (int t = 0; t < 2; t++) {
      af[t]  = *(const bf16x8*)&As[(wm + t * 16 + l15) * 40 + q * 8];
      bfr[t] = *(const bf16x8*)&Bs[(wn + t * 16 + l15) * 40 + q * 8];
    }
#pragma unroll
    for (int i = 0; i < 2; i++)
#pragma unroll
      for (int j = 0; j < 2; j++)
        acc[i][j] = __builtin_amdgcn_mfma_f32_16x16x32_bf16(af[i], bfr[j],
                                                            acc[i][j], 0, 0, 0);
    __syncthreads();
  }

#pragma unroll
  for (int i = 0; i < 2; i++) {
#pragma unroll
    for (int j = 0; j < 2; j++) {
      int col = cb + wn + j * 16 + l15;
#pragma unroll
      for (int r = 0; r < 4; r++) {
        int rr = rb + wm + i * 16 + q * 4 + r;
        Co[(size_t)rr * 512 + col] = acc[i][j][r] + Res[(size_t)rr * 512 + col];
      }
    }
  }
}

// ---------- split-bf16 MFMA GEMM (hi+lo): QKV + gates; v written head-major ----------
__global__ void __launch_bounds__(256)
k_gemm_qkv(const float* __restrict__ A, const ushort* __restrict__ BTh,
           const ushort* __restrict__ BTl, float* __restrict__ Co,
           float* __restrict__ vhm, float* __restrict__ gates, int Kd) {
  __shared__ ushort Ash[64 * 40];
  __shared__ ushort Asl[64 * 40];
  __shared__ ushort Bsh[64 * 40];
  __shared__ ushort Bsl[64 * 40];
  int tid = threadIdx.x;
  int lane = tid & 63, wave = tid >> 6;
  int rb = blockIdx.y * 64, cb = blockIdx.x * 64;
  int wm = (wave >> 1) * 32, wn = (wave & 1) * 32;
  int q = lane >> 4, l15 = lane & 15;
  int srow = tid >> 2, scol = (tid & 3) * 8;

  f32x4 acc[2][2];
#pragma unroll
  for (int i = 0; i < 2; i++)
#pragma unroll
    for (int j = 0; j < 2; j++) acc[i][j] = (f32x4){0.f, 0.f, 0.f, 0.f};

  const float*  ap  = A   + (size_t)(rb + srow) * Kd + scol;
  const ushort* bph = BTh + (size_t)(cb + srow) * Kd + scol;
  const ushort* bpl = BTl + (size_t)(cb + srow) * Kd + scol;
  ushort* awh = &Ash[srow * 40 + scol];
  ushort* awl = &Asl[srow * 40 + scol];
  ushort* bwh = &Bsh[srow * 40 + scol];
  ushort* bwl = &Bsl[srow * 40 + scol];

  for (int k0 = 0; k0 < Kd; k0 += 32) {
    float4 a0 = *(const float4*)(ap + k0);
    float4 a1 = *(const float4*)(ap + k0 + 4);
    float va[8] = {a0.x, a0.y, a0.z, a0.w, a1.x, a1.y, a1.z, a1.w};
    ushort hh[8], hl[8];
#pragma unroll
    for (int e = 0; e < 8; e++) {
      hh[e] = f2b(va[e]);
      hl[e] = f2b(va[e] - b2f(hh[e]));
    }
    *(int4*)awh = *(int4*)hh;
    *(int4*)awl = *(int4*)hl;
    *(int4*)bwh = *(const int4*)(bph + k0);
    *(int4*)bwl = *(const int4*)(bpl + k0);
    __syncthreads();
    bf16x8 afh[2], afl[2], bfh[2], bfl[2];
#pragma unroll
    for (int t = 0; t < 2; t++) {
      int ar = (wm + t * 16 + l15) * 40 + q * 8;
      int br = (wn + t * 16 + l15) * 40 + q * 8;
      afh[t] = *(const bf16x8*)&Ash[ar];
      afl[t] = *(const bf16x8*)&Asl[ar];
      bfh[t] = *(const bf16x8*)&Bsh[br];
      bfl[t] = *(const bf16x8*)&Bsl[br];
    }
#pragma unroll
    for (int i = 0; i < 2; i++)
#pragma unroll
      for (int j = 0; j < 2; j++) {
        acc[i][j] = __builtin_amdgcn_mfma_f32_16x16x32_bf16(afh[i], bfh[j],
                                                            acc[i][j], 0, 0, 0);
        acc[i][j] = __builtin_amdgcn_mfma_f32_16x16x32_bf16(afh[i], bfl[j],
                                                            acc[i][j], 0, 0, 0);
        acc[i][j] = __builtin_amdgcn_mfma_f32_16x16x32_bf16(afl[i], bfh[j],
                                                            acc[i][j], 0, 0, 0);
      }
    __syncthreads();
  }

  const size_t NW = (size_t)NTOK * DIMM;
#pragma unroll
  for (int i = 0; i < 2; i++) {
#pragma unroll
    for (int j = 0; j < 2; j++) {
      int col = cb + wn + j * 16 + l15;
#pragma unroll
      for (int r = 0; r < 4; r++) {
        int row = rb + wm + i * 16 + q * 4 + r;
        float vv = acc[i][j][r];
        if (cb >= 1536) {
          int c24 = col - 1536;
          if (c24 < 24)
            gates[(size_t)row * 24 + c24] = 1.f / (1.f + expf(-vv));
        } else if (col >= 1024) {
          int c = col - 1024;   // v plane -> head-major
          vhm[(size_t)(c >> 6) * 65536 + (size_t)row * 64 + (c & 63)] = vv;
        } else {
          Co[(size_t)(col >> 9) * NW + (size_t)row * 512 + (col & 511)] = vv;
        }
      }
    }
  }
}

// ---------- RoPE: q in-place (token-major); k -> khm (head-major) ----------
__global__ void __launch_bounds__(256)
k_rope(float* __restrict__ q, const float* __restrict__ k,
       float* __restrict__ khm) {
  int idx = blockIdx.x * 256 + threadIdx.x;
  int ten = idx >> 18;
  int r = idx & 262143;
  int j = r & 31;
  int h = (r >> 5) & 7;
  int n = r >> 8;
  float inv = powf(10000.f, -(float)j / 32.f);
  float ang = (float)n * inv;
  float sn, cs;
  sincosf(ang, &sn, &cs);
  size_t base = (size_t)n * DIMM + h * HD + j;
  if (ten == 0) {
    float x1 = q[base], x2 = q[base + 32];
    q[base] = x1 * cs - x2 * sn;
    q[base + 32] = x2 * cs + x1 * sn;
  } else {
    float x1 = k[base], x2 = k[base + 32];
    size_t ob = (size_t)h * 65536 + (size_t)n * 64 + j;
    khm[ob] = x1 * cs - x2 * sn;
    khm[ob + 32] = x2 * cs + x1 * sn;
  }
}

// ---------- compressed k/v via MFMA hi/lo (head-major inputs) ----------
__global__ void __launch_bounds__(256)
k_ckcv_m(const float* __restrict__ khm, const float* __restrict__ vhm,
         const float* __restrict__ k_pos, const float* __restrict__ v_pos,
         const ushort* __restrict__ WckTh, const ushort* __restrict__ WckTl,
         const ushort* __restrict__ WcvTh, const ushort* __restrict__ WcvTl,
         const float* __restrict__ bck, const float* __restrict__ bcv,
         float* __restrict__ ckb, float* __restrict__ cvb) {
  int h = blockIdx.x, kv = blockIdx.y;
  const float* src = kv ? vhm : khm;
  const float* pos = kv ? v_pos : k_pos;
  const ushort* WTh = kv ? WcvTh : WckTh;
  const ushort* WTl = kv ? WcvTl : WckTl;
  const float* bias = kv ? bcv : bck;
  float* outp = kv ? cvb : ckb;

  __shared__ ushort Ash[64 * 72], Asl[64 * 72];
  __shared__ ushort Bsh[64 * 72], Bsl[64 * 72];
  int tid = threadIdx.x;
  int lane = tid & 63, wave = tid >> 6;
  int wm = (wave >> 1) * 32, wn = (wave & 1) * 32;
  int q = lane >> 4, l15 = lane & 15;
  int srow = tid >> 2;
  int e0 = (tid & 3) * 16;

  f32x4 acc[2][2];
#pragma unroll
  for (int i = 0; i < 2; i++)
#pragma unroll
    for (int j = 0; j < 2; j++) acc[i][j] = (f32x4){0.f, 0.f, 0.f, 0.f};

  for (int t = 0; t < 16; t++) {
    const float* ar = src + (size_t)h * 65536 + (size_t)(srow * 16 + t) * 64 + e0;
    const float* pr = pos + (size_t)(h * 16 + t) * HD + e0;
    ushort hh[16], hl[16];
#pragma unroll
    for (int u = 0; u < 4; u++) {
      float4 av = *(const float4*)(ar + u * 4);
      float4 pv = *(const float4*)(pr + u * 4);
      float vals[4] = {av.x + pv.x, av.y + pv.y, av.z + pv.z, av.w + pv.w};
#pragma unroll
      for (int e = 0; e < 4; e++) {
        ushort hb = f2b(vals[e]);
        hh[u * 4 + e] = hb;
        hl[u * 4 + e] = f2b(vals[e] - b2f(hb));
      }
    }
    *(int4*)&Ash[srow * 72 + e0]     = *(int4*)&hh[0];
    *(int4*)&Ash[srow * 72 + e0 + 8] = *(int4*)&hh[8];
    *(int4*)&Asl[srow * 72 + e0]     = *(int4*)&hl[0];
    *(int4*)&Asl[srow * 72 + e0 + 8] = *(int4*)&hl[8];
    const ushort* bh = WTh + (size_t)srow * 1024 + t * 64 + e0;
    const ushort* bl = WTl + (size_t)srow * 1024 + t * 64 + e0;
    *(int4*)&Bsh[srow * 72 + e0]     = *(const int4*)bh;
    *(int4*)&Bsh[srow * 72 + e0 + 8] = *(const int4*)(bh + 8);
    *(int4*)&Bsl[srow * 72 + e0]     = *(const int4*)bl;
    *(int4*)&Bsl[srow * 72 + e0 + 8] = *(const int4*)(bl + 8);
    __syncthreads();
#pragma unroll
    for (int sub = 0; sub < 2; sub++) {
      bf16x8 afh[2], afl[2], bfh[2], bfl[2];
#pragma unroll
      for (int ti = 0; ti < 2; ti++) {
        int ar2 = (wm + ti * 16 + l15) * 72 + sub * 32 + q * 8;
        int br2 = (wn + ti * 16 + l15) * 72 + sub * 32 + q * 8;
        afh[ti] = *(const bf16x8*)&Ash[ar2];
        afl[ti] = *(const bf16x8*)&Asl[ar2];
        bfh[ti] = *(const bf16x8*)&Bsh[br2];
        bfl[ti] = *(const bf16x8*)&Bsl[br2];
      }
#pragma unroll
      for (int i = 0; i < 2; i++)
#pragma unroll
        for (int j = 0; j < 2; j++) {
          acc[i][j] = __builtin_amdgcn_mfma_f32_16x16x32_bf16(afh[i], bfh[j],
                                                              acc[i][j], 0, 0, 0);
          acc[i][j] = __builtin_amdgcn_mfma_f32_16x16x32_bf16(afh[i], bfl[j],
                                                              acc[i][j], 0, 0, 0);
          acc[i][j] = __builtin_amdgcn_mfma_f32_16x16x32_bf16(afl[i], bfh[j],
                                                              acc[i][j], 0, 0, 0);
        }
    }
    __syncthreads();
  }

#pragma unroll
  for (int i = 0; i < 2; i++) {
#pragma unroll
    for (int j = 0; j < 2; j++) {
      int d = wn + j * 16 + l15;
      float bv = bias[d];
#pragma unroll
      for (int r = 0; r < 4; r++) {
        int c = wm + i * 16 + q * 4 + r;
        outp[((size_t)h * 64 + c) * 64 + d] = acc[i][j][r] + bv;
      }
    }
  }
}

// ---------- compressed attention + top-8 (standalone, barrier-light) ----------
__global__ void __launch_bounds__(256)
k_cmp(const float* __restrict__ qg, const float* __restrict__ ckb,
      const float* __restrict__ cvb, const float* __restrict__ k_mem,
      const float* __restrict__ v_mem, float* __restrict__ cout,
      int* __restrict__ sel) {
  int h = blockIdx.y, i0 = blockIdx.x * 16;
  int tid = threadIdx.x, lane = tid & 63, w = tid >> 6;
  __shared__ float ckt[64][65];
  __shared__ float cvs[64][65];
  __shared__ float qs[16][64];
  __shared__ float kms[64], vms[64];
  __shared__ float sp[4][64];

#pragma unroll
  for (int r = 0; r < 4; r++) {
    int f = r * 256 + tid;
    int c = f >> 4, d0 = (f & 15) * 4;
    float4 t = *(const float4*)(ckb + ((size_t)h * 64 + c) * 64 + d0);
    ckt[d0][c] = t.x; ckt[d0 + 1][c] = t.y; ckt[d0 + 2][c] = t.z; ckt[d0 + 3][c] = t.w;
    float4 u = *(const float4*)(cvb + ((size_t)h * 64 + c) * 64 + d0);
    cvs[c][d0] = u.x; cvs[c][d0 + 1] = u.y; cvs[c][d0 + 2] = u.z; cvs[c][d0 + 3] = u.w;
  }
  {
    int r = tid >> 4, d0 = (tid & 15) * 4;
    float4 t = *(const float4*)(qg + (size_t)(i0 + r) * DIMM + h * HD + d0);
    qs[r][d0] = t.x; qs[r][d0 + 1] = t.y; qs[r][d0 + 2] = t.z; qs[r][d0 + 3] = t.w;
  }
  if (tid < 64) kms[tid] = k_mem[h * HD + tid];
  else if (tid < 128) vms[tid - 64] = v_mem[h * HD + tid - 64];
  __syncthreads();

  for (int s = 0; s < 4; s++) {
    int ql = w * 4 + s, qi = i0 + ql;
    float dot = 0.f, dm = 0.f;
#pragma unroll 8
    for (int e = 0; e < 64; e++) {
      float qe = qs[ql][e];
      dot = fmaf(qe, ckt[e][lane], dot);
      dm  = fmaf(qe, kms[e], dm);
    }
    bool vis = (lane * BCB + BCB - 1) < qi;
    float sj = vis ? dot * SCALE : NEGV;
    float smem = dm * SCALE;
    float m = wred_max(fmaxf(sj, smem));
    float p = expf(sj - m);
    float pmem = expf(smem - m);
    float l = wred_sum(p) + pmem;
    float inv = 1.f / l;

    float impv = vis ? p : NEGV;
#pragma unroll
    for (int kk = 0; kk < KSEL; kk++) {
      float bv = impv; int bi = lane;
#pragma unroll
      for (int off = 32; off > 0; off >>= 1) {
        float ov = __shfl_xor(bv, off);
        int   oi = __shfl_xor(bi, off);
        if (ov > bv || (ov == bv && oi < bi)) { bv = ov; bi = oi; }
      }
      if (lane == 0) sel[((size_t)h * NTOK + qi) * KSEL + kk] = (bv >= 0.f) ? bi : -1;
      if (lane == bi) impv = NEGV;
    }

    sp[w][lane] = p;
    float od = pmem * vms[lane];
#pragma unroll 8
    for (int j = 0; j < 64; j++) od = fmaf(sp[w][j], cvs[j][lane], od);
    cout[(size_t)qi * DIMM + h * HD + lane] = od * inv;
  }
}

// ---------- sliding window: MFMA flash. block=(h, 64 q rows), wave owns 16 rows ----------
__global__ void __launch_bounds__(256)
k_swin(const float* __restrict__ qg, const float* __restrict__ khm,
       const float* __restrict__ vhm, float* __restrict__ sout) {
  int h = blockIdx.y, i0 = blockIdx.x * 64;
  int tid = threadIdx.x, lane = tid & 63, w = tid >> 6;
  int quad = lane >> 4, l15 = lane & 15;

  __shared__ ushort Kt[64 * 72];
  __shared__ ushort VT[64 * 72];
  __shared__ ushort Qs[64 * 72];
  __shared__ ushort Ps[4][16 * 72];

#pragma unroll
  for (int it = 0; it < 4; it++) {
    int f = it * 256 + tid;
    int r = f >> 4, d0 = (f & 15) * 4;
    float4 t = *(const float4*)(qg + (size_t)(i0 + r) * DIMM + h * HD + d0);
    ushort4 u = {f2b(t.x), f2b(t.y), f2b(t.z), f2b(t.w)};
    *(ushort4*)&Qs[r * 72 + d0] = u;
  }

  int lo = i0 - (WWIN - 1); if (lo < 0) lo = 0;
  int jb_lo = lo >> 6, jb_hi = (i0 + 63) >> 6;

  float mrow[4], lrow[4];
  f32x4 Of[4];
#pragma unroll
  for (int r = 0; r < 4; r++) { mrow[r] = NEGV; lrow[r] = 0.f; }
#pragma unroll
  for (int d = 0; d < 4; d++) Of[d] = (f32x4){0.f, 0.f, 0.f, 0.f};

  for (int jb = jb_lo; jb <= jb_hi; jb++) {
    __syncthreads();
#pragma unroll
    for (int it = 0; it < 4; it++) {
      int f = it * 256 + tid;
      int r = f >> 4, d0 = (f & 15) * 4;
      const float* kp = khm + (size_t)h * 65536 + (size_t)(jb * 64 + r) * 64 + d0;
      float4 t = *(const float4*)kp;
      ushort4 u = {f2b(t.x), f2b(t.y), f2b(t.z), f2b(t.w)};
      *(ushort4*)&Kt[r * 72 + d0] = u;
      const float* vp = vhm + (size_t)h * 65536 + (size_t)(jb * 64 + r) * 64 + d0;
      float4 v4 = *(const float4*)vp;
      VT[(d0    ) * 72 + r] = f2b(v4.x);
      VT[(d0 + 1) * 72 + r] = f2b(v4.y);
      VT[(d0 + 2) * 72 + r] = f2b(v4.z);
      VT[(d0 + 3) * 72 + r] = f2b(v4.w);
    }
    __syncthreads();

    bf16x8 qa[2];
#pragma unroll
    for (int c = 0; c < 2; c++)
      qa[c] = *(const bf16x8*)&Qs[(w * 16 + l15) * 72 + c * 32 + quad * 8];

    f32x4 sc[4];
#pragma unroll
    for (int ks = 0; ks < 4; ks++) {
      f32x4 a = (f32x4){0.f, 0.f, 0.f, 0.f};
#pragma unroll
      for (int c = 0; c < 2; c++) {
        bf16x8 kb = *(const bf16x8*)&Kt[(ks * 16 + l15) * 72 + c * 32 + quad * 8];
        a = __builtin_amdgcn_mfma_f32_16x16x32_bf16(qa[c], kb, a, 0, 0, 0);
      }
      sc[ks] = a;
    }

    float pm[4][4], rmax[4];
#pragma unroll
    for (int r = 0; r < 4; r++) rmax[r] = NEGV;
#pragma unroll
    for (int ks = 0; ks < 4; ks++) {
      int gj = jb * 64 + ks * 16 + l15;
#pragma unroll
      for (int r = 0; r < 4; r++) {
        int qi = i0 + w * 16 + quad * 4 + r;
        bool vis = (gj <= qi) && (qi - gj < WWIN);
        float s = vis ? sc[ks][r] * SCALE : NEGV;
        pm[ks][r] = s;
        rmax[r] = fmaxf(rmax[r], s);
      }
    }
#pragma unroll
    for (int off = 1; off < 16; off <<= 1)
#pragma unroll
      for (int r = 0; r < 4; r++)
        rmax[r] = fmaxf(rmax[r], __shfl_xor(rmax[r], off));

    float alpha[4], rsum[4];
#pragma unroll
    for (int r = 0; r < 4; r++) {
      float newm = fmaxf(mrow[r], rmax[r]);
      alpha[r] = expf(mrow[r] - newm);
      mrow[r] = newm;
      rsum[r] = 0.f;
    }
#pragma unroll
    for (int ks = 0; ks < 4; ks++)
#pragma unroll
      for (int r = 0; r < 4; r++) {
        float p = expf(pm[ks][r] - mrow[r]);
        pm[ks][r] = p;
        rsum[r] += p;
      }
#pragma unroll
    for (int off = 1; off < 16; off <<= 1)
#pragma unroll
      for (int r = 0; r < 4; r++)
        rsum[r] += __shfl_xor(rsum[r], off);
#pragma unroll
    for (int r = 0; r < 4; r++)
      lrow[r] = lrow[r] * alpha[r] + rsum[r];

#pragma unroll
    for (int ks = 0; ks < 4; ks++)
#pragma unroll
      for (int r = 0; r < 4; r++)
        Ps[w][(quad * 4 + r) * 72 + ks * 16 + l15] = f2b(pm[ks][r]);
#pragma unroll
    for (int d = 0; d < 4; d++)
#pragma unroll
      for (int r = 0; r < 4; r++)
        Of[d][r] *= alpha[r];

#pragma unroll
    for (int c = 0; c < 2; c++) {
      bf16x8 pa = *(const bf16x8*)&Ps[w][l15 * 72 + c * 32 + quad * 8];
#pragma unroll
      for (int d = 0; d < 4; d++) {
        bf16x8 vb = *(const bf16x8*)&VT[(d * 16 + l15) * 72 + c * 32 + quad * 8];
        Of[d] = __builtin_amdgcn_mfma_f32_16x16x32_bf16(pa, vb, Of[d], 0, 0, 0);
      }
    }
  }

#pragma unroll
  for (int d = 0; d < 4; d++)
#pragma unroll
    for (int r = 0; r < 4; r++) {
      int qi = i0 + w * 16 + quad * 4 + r;
      sout[(size_t)qi * DIMM + h * HD + d * 16 + l15] = Of[d][r] / lrow[r];
    }
}

// ---------- fine attention: direct QK gather + bf16 V staged in LDS ----------
__global__ void __launch_bounds__(256)
k_fine(const float* __restrict__ qg, const float* __restrict__ khm,
       const float* __restrict__ vhm, const int* __restrict__ sel,
       float* __restrict__ fout) {
  int i = blockIdx.x, h = blockIdx.y;
  int tid = threadIdx.x, lane = tid & 63, w = tid >> 6;
  __shared__ float qsh[64];
  __shared__ ushort vsb[144 * 64];
  __shared__ float sp[144];
  __shared__ int selS[8];
  __shared__ float mred[4], sredS[4];
  __shared__ float pacc[4][64];

  int own = i >> 4;
  if (tid < 64) qsh[tid] = qg[(size_t)i * DIMM + h * HD + tid];
  if (tid >= 64 && tid < 72)
    selS[tid - 64] = sel[((size_t)h * NTOK + i) * KSEL + tid - 64];
  __syncthreads();

  const float* kbase = khm + (size_t)h * 65536;
  const float* vbase = vhm + (size_t)h * 65536;

#pragma unroll
  for (int it = 0; it < 9; it++) {
    int idx = it * 256 + tid;
    int row = idx >> 4, c4 = (idx & 15) * 4;
    int kk = row >> 4;
    int bidx = (kk < KSEL) ? selS[kk] : own;
    if (bidx < 0) bidx = 0;
    float4 t = *(const float4*)(vbase + (size_t)(bidx * BSB + (row & 15)) * 64 + c4);
    ushort4 u = {f2b(t.x), f2b(t.y), f2b(t.z), f2b(t.w)};
    *(ushort4*)&vsb[row * 64 + c4] = u;
  }

  float s_loc = NEGV;
  bool active = (tid < 144);
  if (active) {
    int kk = tid >> 4;
    int bidx; bool vis;
    if (kk < KSEL) {
      bidx = selS[kk];
      vis = (bidx >= 0);
      if (!vis) bidx = 0;
    } else {
      bidx = own;
      vis = (tid - 128) <= (i & 15);
    }
    const float* kr = kbase + (size_t)(bidx * BSB + (tid & 15)) * 64;
    float dot = 0.f;
#pragma unroll
    for (int e4 = 0; e4 < 16; e4++) {
      float4 kv = *(const float4*)(kr + e4 * 4);
      float4 qv = *(const float4*)&qsh[e4 * 4];
      dot = fmaf(qv.x, kv.x, dot); dot = fmaf(qv.y, kv.y, dot);
      dot = fmaf(qv.z, kv.z, dot); dot = fmaf(qv.w, kv.w, dot);
    }
    s_loc = vis ? dot * SCALE : NEGV;
  }
  float mw = wred_max(s_loc);
  if (lane == 0) mred[w] = mw;
  __syncthreads();
  float m = fmaxf(fmaxf(mred[0], mred[1]), fmaxf(mred[2], mred[3]));
  float p = active ? expf(s_loc - m) : 0.f;
  float sw = wred_sum(p);
  if (lane == 0) sredS[w] = sw;
  if (active) sp[tid] = p;
  __syncthreads();
  float l = sredS[0] + sredS[1] + sredS[2] + sredS[3];

  float acc = 0.f;
  int j0 = w * 36;
#pragma unroll 6
  for (int jj = 0; jj < 36; jj++) {
    int j = j0 + jj;
    acc = fmaf(sp[j], b2f(vsb[j * 64 + lane]), acc);
  }
  pacc[w][lane] = acc;
  __syncthreads();
  if (w == 0)
    fout[(size_t)i * DIMM + h * HD + lane] =
        (pacc[0][lane] + pacc[1][lane] + pacc[2][lane] + pacc[3][lane]) / l;
}

extern "C" void kernel_launch(void* const* d_in, const int* in_sizes, int n_in,
                              void* d_out, int out_size, void* d_ws, size_t ws_size,
                              hipStream_t stream) {
  const float* x     = (const float*)d_in[0];
  const float* ve    = (const float*)d_in[1]; (void)ve;
  const float* x0    = (const float*)d_in[2];
  const float* lam   = (const float*)d_in[3];
  const float* Wq    = (const float*)d_in[4];
  const float* Wk    = (const float*)d_in[5];
  const float* Wv    = (const float*)d_in[6];
  const float* Wo    = (const float*)d_in[7];
  const float* Wg    = (const float*)d_in[8];
  const float* k_pos = (const float*)d_in[9];
  const float* v_pos = (const float*)d_in[10];
  const float* Wck   = (const float*)d_in[11];
  const float* bck   = (const float*)d_in[12];
  const float* Wcv   = (const float*)d_in[13];
  const float* bcv   = (const float*)d_in[14];
  const float* k_mem = (const float*)d_in[15];
  const float* v_mem = (const float*)d_in[16];
  const float* W1    = (const float*)d_in[17];
  const float* W2    = (const float*)d_in[18];
  float* out = (float*)d_out;
  float* ws  = (float*)d_ws;

  const size_t NW = (size_t)NTOK * DIMM;   // 524288
  float* xr    = ws;
  float* xn    = ws + 1 * NW;
  float* q     = ws + 2 * NW;
  float* k     = ws + 3 * NW;     // token-major k (dead after rope)
  float* vhm   = ws + 4 * NW;     // head-major v (written by QKV epilogue)
  float* coutb = ws + 5 * NW;
  float* foutb = ws + 6 * NW;
  float* soutb = ws + 7 * NW;
  float* x2    = ws + 8 * NW;     // khm until gemm_wo overwrites as x2
  float* khm   = x2;
  float* gates = ws + 9 * NW;
  float* ckb   = gates + 32768;
  float* cvb   = ckb + 32768;
  int*   selb  = (int*)(cvb + 32768);
  ushort* qkvTh = (ushort*)(cvb + 32768 + 65536);
  ushort* qkvTl = qkvTh + 1600 * 512;
  ushort* WoT   = qkvTl + 1600 * 512;
  ushort* W1T   = WoT   + 512 * 512;
  ushort* W2T   = W1T   + 2048 * 512;
  ushort* WckTh = W2T   + 512 * 2048;
  ushort* WckTl = WckTh + 64 * 1024;
  ushort* WcvTh = WckTl + 64 * 1024;
  ushort* WcvTl = WcvTh + 64 * 1024;
  ushort* ybf = (ushort*)xr;     // bf16 y, reuse xr after Wo consumed it
  ushort* h1b = (ushort*)q;      // bf16 h1 (1024x2048 = 4MB), q dead post-Wo

  WtrPack pk;
  pk.d[0] = {Wq, qkvTh,              qkvTl,              512, 512,  512};
  pk.d[1] = {Wk, qkvTh + 512 * 512,  qkvTl + 512 * 512,  512, 512,  512};
  pk.d[2] = {Wv, qkvTh + 1024 * 512, qkvTl + 1024 * 512, 512, 512,  512};
  pk.d[3] = {Wo, WoT, nullptr,  512, 512,  512};
  pk.d[4] = {W1, W1T, nullptr,  512, 2048, 2048};
  pk.d[5] = {W2, W2T, nullptr, 2048, 512,  512};
  pk.d[6] = {Wck, WckTh, WckTl, 1024, 64, 64};
  pk.d[7] = {Wcv, WcvTh, WcvTl, 1024, 64, 64};
  pk.d[8] = {Wg, qkvTh + 1536 * 512, qkvTl + 1536 * 512, 512, 24, 64};
  int cum = 0;
  for (int e = 0; e < 9; e++) {
    cum += (pk.d[e].Npad / 32) * (pk.d[e].K / 32);
    pk.cum[e] = cum;
  }
  k_wtr_all<<<cum, dim3(32, 8), 0, stream>>>(pk);

  k_resid_rms<<<NTOK, 256, 0, stream>>>(x, x0, lam, xr, xn);

  k_gemm_qkv<<<dim3(25, NTOK / 64), 256, 0, stream>>>(
      xn, qkvTh, qkvTl, q, vhm, gates, 512);
  k_rope<<<(2 * NTOK * NH * 32) / 256, 256, 0, stream>>>(q, k, khm);

  k_ckcv_m<<<dim3(NH, 2), 256, 0, stream>>>(khm, vhm, k_pos, v_pos,
                                            WckTh, WckTl, WcvTh, WcvTl,
                                            bck, bcv, ckb, cvb);
  k_cmp<<<dim3(NTOK / 16, NH), 256, 0, stream>>>(q, ckb, cvb, k_mem, v_mem,
                                                 coutb, selb);
  k_swin<<<dim3(NTOK / 64, NH), 256, 0, stream>>>(q, khm, vhm, soutb);
  k_fine<<<dim3(NTOK, NH), 256, 0, stream>>>(q, khm, vhm, selb, foutb);

  k_gemm_wo<<<dim3(512 / 64, NTOK / 64), 256, 0, stream>>>(
      coutb, foutb, soutb, gates, WoT, xr, x2);

  k_rms_bf<<<NTOK, 256, 0, stream>>>(x2, ybf);
  k_gemm_mlp<<<dim3(2048 / 128, NTOK / 128), 256, 0, stream>>>(
      ybf, W1T, nullptr, h1b, 512, 2048, 1);
  k_gemm_mlp<<<dim3(512 / 128, NTOK / 128), 256, 0, stream>>>(
      h1b, W2T, x2, out, 2048, 512, 2);
}

// Round 10
// 298.936 us; speedup vs baseline: 1.1951x; 1.1951x over previous
//
#include <hip/hip_runtime.h>
#include <math.h>

#define NTOK 1024
#define DIMM 512
#define NH 8
#define HD 64
#define BCB 16
#define BSB 16
#define KSEL 8
#define WWIN 256
#define CBLK 64
#define SCALE 0.125f
#define EPSV 1e-6f
#define NEGV -1e30f

typedef short bf16x8 __attribute__((ext_vector_type(8)));
typedef float f32x4 __attribute__((ext_vector_type(4)));

__device__ inline ushort f2b(float f) {
  union { float f; unsigned int u; } c; c.f = f;
  unsigned int u = c.u;
  return (ushort)((u + 0x7FFFu + ((u >> 16) & 1u)) >> 16);
}
__device__ inline float b2f(ushort h) {
  union { unsigned int u; float f; } c; c.u = ((unsigned int)h) << 16;
  return c.f;
}

__device__ inline float wred_max(float v) {
#pragma unroll
  for (int off = 1; off < 64; off <<= 1) v = fmaxf(v, __shfl_xor(v, off));
  return v;
}
__device__ inline float wred_sum(float v) {
#pragma unroll
  for (int off = 1; off < 64; off <<= 1) v += __shfl_xor(v, off);
  return v;
}

// ---------- residual mix + rmsnorm ----------
__global__ void __launch_bounds__(256)
k_resid_rms(const float* __restrict__ x, const float* __restrict__ x0,
            const float* __restrict__ lam, float* __restrict__ xr,
            float* __restrict__ xn) {
  int row = blockIdx.x, tid = threadIdx.x;
  float l0 = lam[0], l1 = lam[1];
  size_t b = (size_t)row * DIMM;
  float a0 = l0 * x[b + tid]       + l1 * x0[b + tid];
  float a1 = l0 * x[b + tid + 256] + l1 * x0[b + tid + 256];
  xr[b + tid] = a0; xr[b + tid + 256] = a1;
  float ss = a0 * a0 + a1 * a1;
  __shared__ float sm[8];
  for (int o = 32; o > 0; o >>= 1) ss += __shfl_down(ss, o);
  int lane = tid & 63, wid = tid >> 6;
  if (lane == 0) sm[wid] = ss;
  __syncthreads();
  if (tid == 0) {
    float s = sm[0] + sm[1] + sm[2] + sm[3];
    sm[0] = rsqrtf(s / (float)DIMM + EPSV);
  }
  __syncthreads();
  float r = sm[0];
  xn[b + tid] = a0 * r; xn[b + tid + 256] = a1 * r;
}

// ---------- rmsnorm -> bf16 output ----------
__global__ void __launch_bounds__(256)
k_rms_bf(const float* __restrict__ xin, ushort* __restrict__ y) {
  int row = blockIdx.x, tid = threadIdx.x;
  size_t b = (size_t)row * DIMM;
  float a0 = xin[b + tid], a1 = xin[b + tid + 256];
  float ss = a0 * a0 + a1 * a1;
  __shared__ float sm[8];
  for (int o = 32; o > 0; o >>= 1) ss += __shfl_down(ss, o);
  int lane = tid & 63, wid = tid >> 6;
  if (lane == 0) sm[wid] = ss;
  __syncthreads();
  if (tid == 0) {
    float s = sm[0] + sm[1] + sm[2] + sm[3];
    sm[0] = rsqrtf(s / (float)DIMM + EPSV);
  }
  __syncthreads();
  float r = sm[0];
  y[b + tid] = f2b(a0 * r); y[b + tid + 256] = f2b(a1 * r);
}

// ---------- consolidated weight transposes (f32 K×N -> bf16 hi/lo N×K) ----------
struct WtrDesc { const float* src; ushort* dh; ushort* dl; int K; int Nsrc; int Npad; };
struct WtrPack { WtrDesc d[9]; int cum[9]; };

__global__ void __launch_bounds__(256)
k_wtr_all(WtrPack pk) {
  int gb = blockIdx.x;
  int e = 0;
  while (gb >= pk.cum[e]) e++;
  int start = e ? pk.cum[e - 1] : 0;
  WtrDesc dd = pk.d[e];
  int local = gb - start;
  int XT = dd.Npad >> 5;
  int bx = local % XT, by = local / XT;
  __shared__ float t[32][33];
  int n0 = bx * 32, k0 = by * 32;
  int tx = threadIdx.x, ty = threadIdx.y;  // 32 x 8
#pragma unroll
  for (int i = 0; i < 32; i += 8)
    t[ty + i][tx] = (n0 + tx < dd.Nsrc)
        ? dd.src[(size_t)(k0 + ty + i) * dd.Nsrc + n0 + tx] : 0.f;
  __syncthreads();
#pragma unroll
  for (int i = 0; i < 32; i += 8) {
    float vv = t[tx][ty + i];
    ushort h = f2b(vv);
    size_t di = (size_t)(n0 + ty + i) * dd.K + k0 + tx;
    dd.dh[di] = h;
    if (dd.dl) dd.dl[di] = f2b(vv - b2f(h));
  }
}

// ---------- W1 GEMM: 128Mx64N tile, A bf16, relu^2 -> bf16. grid (32,8) ----------
__global__ void __launch_bounds__(256)
k_gemm_w1(const ushort* __restrict__ A, const ushort* __restrict__ BT,
          ushort* __restrict__ Co) {
  const int Kd = 512, Nd = 2048;
  __shared__ ushort As[128 * 40];
  __shared__ ushort Bs[64 * 40];
  int tid = threadIdx.x;
  int lane = tid & 63, w = tid >> 6;
  int rb = blockIdx.y * 128, cb = blockIdx.x * 64;
  int wm = (w >> 1) * 64, wn = (w & 1) * 32;
  int quad = lane >> 4, l15 = lane & 15;
  int srA = tid >> 1, scA = (tid & 1) * 16;
  int srB = tid >> 2, scB = (tid & 3) * 8;

  f32x4 acc[4][2];
#pragma unroll
  for (int i = 0; i < 4; i++)
#pragma unroll
    for (int j = 0; j < 2; j++) acc[i][j] = (f32x4){0.f, 0.f, 0.f, 0.f};

  const ushort* ap = A  + (size_t)(rb + srA) * Kd + scA;
  const ushort* bp = BT + (size_t)(cb + srB) * Kd + scB;
  ushort* aw = &As[srA * 40 + scA];
  ushort* bw = &Bs[srB * 40 + scB];

  int4 pa0 = *(const int4*)ap;
  int4 pa1 = *(const int4*)(ap + 8);
  int4 pb  = *(const int4*)bp;

  for (int k0 = 0; k0 < Kd; k0 += 32) {
    if (k0) __syncthreads();
    *(int4*)aw = pa0; *(int4*)(aw + 8) = pa1;
    *(int4*)bw = pb;
    __syncthreads();
    if (k0 + 32 < Kd) {
      pa0 = *(const int4*)(ap + k0 + 32);
      pa1 = *(const int4*)(ap + k0 + 40);
      pb  = *(const int4*)(bp + k0 + 32);
    }
    bf16x8 af[4], bfr[2];
#pragma unroll
    for (int t = 0; t < 4; t++)
      af[t] = *(const bf16x8*)&As[(wm + t * 16 + l15) * 40 + quad * 8];
#pragma unroll
    for (int t = 0; t < 2; t++)
      bfr[t] = *(const bf16x8*)&Bs[(wn + t * 16 + l15) * 40 + quad * 8];
#pragma unroll
    for (int i = 0; i < 4; i++)
#pragma unroll
      for (int j = 0; j < 2; j++)
        acc[i][j] = __builtin_amdgcn_mfma_f32_16x16x32_bf16(af[i], bfr[j],
                                                            acc[i][j], 0, 0, 0);
  }

#pragma unroll
  for (int i = 0; i < 4; i++) {
#pragma unroll
    for (int j = 0; j < 2; j++) {
      int col = cb + wn + j * 16 + l15;
#pragma unroll
      for (int r = 0; r < 4; r++) {
        int row = rb + wm + i * 16 + quad * 4 + r;
        float t = fmaxf(acc[i][j][r], 0.f);
        Co[(size_t)row * Nd + col] = f2b(t * t);
      }
    }
  }
}

// ---------- W2 GEMM: 64x64 tile, split-K (z = slice of 1024), f32 partial out ----------
__global__ void __launch_bounds__(256)
k_gemm_w2(const ushort* __restrict__ A, const ushort* __restrict__ BT,
          float* __restrict__ P0, float* __restrict__ P1) {
  const int Kd = 2048;
  __shared__ ushort As[64 * 40];
  __shared__ ushort Bs[64 * 40];
  int tid = threadIdx.x;
  int lane = tid & 63, w = tid >> 6;
  int rb = blockIdx.y * 64, cb = blockIdx.x * 64;
  int kb = blockIdx.z * 1024;
  int wm = (w >> 1) * 32, wn = (w & 1) * 32;
  int quad = lane >> 4, l15 = lane & 15;
  int srow = tid >> 2, scol = (tid & 3) * 8;

  f32x4 acc[2][2];
#pragma unroll
  for (int i = 0; i < 2; i++)
#pragma unroll
    for (int j = 0; j < 2; j++) acc[i][j] = (f32x4){0.f, 0.f, 0.f, 0.f};

  const ushort* ap = A  + (size_t)(rb + srow) * Kd + kb + scol;
  const ushort* bp = BT + (size_t)(cb + srow) * Kd + kb + scol;
  ushort* aw = &As[srow * 40 + scol];
  ushort* bw = &Bs[srow * 40 + scol];

  int4 pa = *(const int4*)ap;
  int4 pb = *(const int4*)bp;

  for (int k0 = 0; k0 < 1024; k0 += 32) {
    if (k0) __syncthreads();
    *(int4*)aw = pa;
    *(int4*)bw = pb;
    __syncthreads();
    if (k0 + 32 < 1024) {
      pa = *(const int4*)(ap + k0 + 32);
      pb = *(const int4*)(bp + k0 + 32);
    }
    bf16x8 af[2], bfr[2];
#pragma unroll
    for (int t = 0; t < 2; t++) {
      af[t]  = *(const bf16x8*)&As[(wm + t * 16 + l15) * 40 + quad * 8];
      bfr[t] = *(const bf16x8*)&Bs[(wn + t * 16 + l15) * 40 + quad * 8];
    }
#pragma unroll
    for (int i = 0; i < 2; i++)
#pragma unroll
      for (int j = 0; j < 2; j++)
        acc[i][j] = __builtin_amdgcn_mfma_f32_16x16x32_bf16(af[i], bfr[j],
                                                            acc[i][j], 0, 0, 0);
  }

  float* pbuf = blockIdx.z ? P1 : P0;
#pragma unroll
  for (int i = 0; i < 2; i++) {
#pragma unroll
    for (int j = 0; j < 2; j++) {
      int col = cb + wn + j * 16 + l15;
#pragma unroll
      for (int r = 0; r < 4; r++) {
        int row = rb + wm + i * 16 + quad * 4 + r;
        pbuf[(size_t)row * 512 + col] = acc[i][j][r];
      }
    }
  }
}

// ---------- W2 finalize: out = x2 + p0 + p1 ----------
__global__ void __launch_bounds__(256)
k_w2fin(const float* __restrict__ x2, const float* __restrict__ p0,
        const float* __restrict__ p1, float* __restrict__ out) {
  int idx = blockIdx.x * 256 + threadIdx.x;
  out[idx] = x2[idx] + p0[idx] + p1[idx];
}

// ---------- Wo GEMM with fused gated combine in A-staging ----------
__global__ void __launch_bounds__(256)
k_gemm_wo(const float* __restrict__ cg, const float* __restrict__ fg,
          const float* __restrict__ sg, const float* __restrict__ gates,
          const ushort* __restrict__ BT, const float* __restrict__ Res,
          float* __restrict__ Co) {
  __shared__ ushort As[64 * 40];
  __shared__ ushort Bs[64 * 40];
  int tid = threadIdx.x;
  int lane = tid & 63, wave = tid >> 6;
  int rb = blockIdx.y * 64, cb = blockIdx.x * 64;
  int wm = (wave >> 1) * 32, wn = (wave & 1) * 32;
  int q = lane >> 4, l15 = lane & 15;
  int srow = tid >> 2, scol = (tid & 3) * 8;

  f32x4 acc[2][2];
#pragma unroll
  for (int i = 0; i < 2; i++)
#pragma unroll
    for (int j = 0; j < 2; j++) acc[i][j] = (f32x4){0.f, 0.f, 0.f, 0.f};

  int row = rb + srow;
  const ushort* bp = BT + (size_t)(cb + srow) * 512 + scol;
  ushort* aw = &As[srow * 40 + scol];
  ushort* bw = &Bs[srow * 40 + scol];

  for (int k0 = 0; k0 < 512; k0 += 32) {
    int colb = k0 + scol;
    int hh = colb >> 6;
    const float* gp = gates + (size_t)row * 24 + hh * 3;
    float g0 = gp[0], g1 = gp[1], g2 = gp[2];
    size_t off = (size_t)row * 512 + colb;
    float4 c0 = *(const float4*)(cg + off), c1 = *(const float4*)(cg + off + 4);
    float4 f0 = *(const float4*)(fg + off), f1 = *(const float4*)(fg + off + 4);
    float4 s0 = *(const float4*)(sg + off), s1 = *(const float4*)(sg + off + 4);
    float va[8] = {g0 * c0.x + g1 * f0.x + g2 * s0.x,
                   g0 * c0.y + g1 * f0.y + g2 * s0.y,
                   g0 * c0.z + g1 * f0.z + g2 * s0.z,
                   g0 * c0.w + g1 * f0.w + g2 * s0.w,
                   g0 * c1.x + g1 * f1.x + g2 * s1.x,
                   g0 * c1.y + g1 * f1.y + g2 * s1.y,
                   g0 * c1.z + g1 * f1.z + g2 * s1.z,
                   g0 * c1.w + g1 * f1.w + g2 * s1.w};
    ushort h[8];
#pragma unroll
    for (int e = 0; e < 8; e++) h[e] = f2b(va[e]);
    *(int4*)aw = *(int4*)h;
    *(int4*)bw = *(const int4*)(bp + k0);
    __syncthreads();
    bf16x8 af[2], bfr[2];
#pragma unroll
    for (int t = 0; t < 2; t++) {
      af[t]  = *(const bf16x8*)&As[(wm + t * 16 + l15) * 40 + q * 8];
      bfr[t] = *(const bf16x8*)&Bs[(wn + t * 16 + l15) * 40 + q * 8];
    }
#pragma unroll
    for (int i = 0; i < 2; i++)
#pragma unroll
      for (int j = 0; j < 2; j++)
        acc[i][j] = __builtin_amdgcn_mfma_f32_16x16x32_bf16(af[i], bfr[j],
                                                            acc[i][j], 0, 0, 0);
    __syncthreads();
  }

#pragma unroll
  for (int i = 0; i < 2; i++) {
#pragma unroll
    for (int j = 0; j < 2; j++) {
      int col = cb + wn + j * 16 + l15;
#pragma unroll
      for (int r = 0; r < 4; r++) {
        int rr = rb + wm + i * 16 + q * 4 + r;
        Co[(size_t)rr * 512 + col] = acc[i][j][r] + Res[(size_t)rr * 512 + col];
      }
    }
  }
}

// ---------- split-bf16 MFMA GEMM (hi+lo): QKV + gates; v written head-major ----------
__global__ void __launch_bounds__(256)
k_gemm_qkv(const float* __restrict__ A, const ushort* __restrict__ BTh,
           const ushort* __restrict__ BTl, float* __restrict__ Co,
           float* __restrict__ vhm, float* __restrict__ gates, int Kd) {
  __shared__ ushort Ash[64 * 40];
  __shared__ ushort Asl[64 * 40];
  __shared__ ushort Bsh[64 * 40];
  __shared__ ushort Bsl[64 * 40];
  int tid = threadIdx.x;
  int lane = tid & 63, wave = tid >> 6;
  int rb = blockIdx.y * 64, cb = blockIdx.x * 64;
  int wm = (wave >> 1) * 32, wn = (wave & 1) * 32;
  int q = lane >> 4, l15 = lane & 15;
  int srow = tid >> 2, scol = (tid & 3) * 8;

  f32x4 acc[2][2];
#pragma unroll
  for (int i = 0; i < 2; i++)
#pragma unroll
    for (int j = 0; j < 2; j++) acc[i][j] = (f32x4){0.f, 0.f, 0.f, 0.f};

  const float*  ap  = A   + (size_t)(rb + srow) * Kd + scol;
  const ushort* bph = BTh + (size_t)(cb + srow) * Kd + scol;
  const ushort* bpl = BTl + (size_t)(cb + srow) * Kd + scol;
  ushort* awh = &Ash[srow * 40 + scol];
  ushort* awl = &Asl[srow * 40 + scol];
  ushort* bwh = &Bsh[srow * 40 + scol];
  ushort* bwl = &Bsl[srow * 40 + scol];

  for (int k0 = 0; k0 < Kd; k0 += 32) {
    float4 a0 = *(const float4*)(ap + k0);
    float4 a1 = *(const float4*)(ap + k0 + 4);
    float va[8] = {a0.x, a0.y, a0.z, a0.w, a1.x, a1.y, a1.z, a1.w};
    ushort hh[8], hl[8];
#pragma unroll
    for (int e = 0; e < 8; e++) {
      hh[e] = f2b(va[e]);
      hl[e] = f2b(va[e] - b2f(hh[e]));
    }
    *(int4*)awh = *(int4*)hh;
    *(int4*)awl = *(int4*)hl;
    *(int4*)bwh = *(const int4*)(bph + k0);
    *(int4*)bwl = *(const int4*)(bpl + k0);
    __syncthreads();
    bf16x8 afh[2], afl[2], bfh[2], bfl[2];
#pragma unroll
    for (int t = 0; t < 2; t++) {
      int ar = (wm + t * 16 + l15) * 40 + q * 8;
      int br = (wn + t * 16 + l15) * 40 + q * 8;
      afh[t] = *(const bf16x8*)&Ash[ar];
      afl[t] = *(const bf16x8*)&Asl[ar];
      bfh[t] = *(const bf16x8*)&Bsh[br];
      bfl[t] = *(const bf16x8*)&Bsl[br];
    }
#pragma unroll
    for (int i = 0; i < 2; i++)
#pragma unroll
      for (int j = 0; j < 2; j++) {
        acc[i][j] = __builtin_amdgcn_mfma_f32_16x16x32_bf16(afh[i], bfh[j],
                                                            acc[i][j], 0, 0, 0);
        acc[i][j] = __builtin_amdgcn_mfma_f32_16x16x32_bf16(afh[i], bfl[j],
                                                            acc[i][j], 0, 0, 0);
        acc[i][j] = __builtin_amdgcn_mfma_f32_16x16x32_bf16(afl[i], bfh[j],
                                                            acc[i][j], 0, 0, 0);
      }
    __syncthreads();
  }

  const size_t NW = (size_t)NTOK * DIMM;
#pragma unroll
  for (int i = 0; i < 2; i++) {
#pragma unroll
    for (int j = 0; j < 2; j++) {
      int col = cb + wn + j * 16 + l15;
#pragma unroll
      for (int r = 0; r < 4; r++) {
        int row = rb + wm + i * 16 + q * 4 + r;
        float vv = acc[i][j][r];
        if (cb >= 1536) {
          int c24 = col - 1536;
          if (c24 < 24)
            gates[(size_t)row * 24 + c24] = 1.f / (1.f + expf(-vv));
        } else if (col >= 1024) {
          int c = col - 1024;   // v plane -> head-major
          vhm[(size_t)(c >> 6) * 65536 + (size_t)row * 64 + (c & 63)] = vv;
        } else {
          Co[(size_t)(col >> 9) * NW + (size_t)row * 512 + (col & 511)] = vv;
        }
      }
    }
  }
}

// ---------- RoPE: q in-place (token-major); k -> khm (head-major) ----------
__global__ void __launch_bounds__(256)
k_rope(float* __restrict__ q, const float* __restrict__ k,
       float* __restrict__ khm) {
  int idx = blockIdx.x * 256 + threadIdx.x;
  int ten = idx >> 18;
  int r = idx & 262143;
  int j = r & 31;
  int h = (r >> 5) & 7;
  int n = r >> 8;
  float inv = powf(10000.f, -(float)j / 32.f);
  float ang = (float)n * inv;
  float sn, cs;
  sincosf(ang, &sn, &cs);
  size_t base = (size_t)n * DIMM + h * HD + j;
  if (ten == 0) {
    float x1 = q[base], x2 = q[base + 32];
    q[base] = x1 * cs - x2 * sn;
    q[base + 32] = x2 * cs + x1 * sn;
  } else {
    float x1 = k[base], x2 = k[base + 32];
    size_t ob = (size_t)h * 65536 + (size_t)n * 64 + j;
    khm[ob] = x1 * cs - x2 * sn;
    khm[ob + 32] = x2 * cs + x1 * sn;
  }
}

// ---------- compressed k/v via MFMA hi/lo (head-major inputs) ----------
__global__ void __launch_bounds__(256)
k_ckcv_m(const float* __restrict__ khm, const float* __restrict__ vhm,
         const float* __restrict__ k_pos, const float* __restrict__ v_pos,
         const ushort* __restrict__ WckTh, const ushort* __restrict__ WckTl,
         const ushort* __restrict__ WcvTh, const ushort* __restrict__ WcvTl,
         const float* __restrict__ bck, const float* __restrict__ bcv,
         float* __restrict__ ckb, float* __restrict__ cvb) {
  int h = blockIdx.x, kv = blockIdx.y;
  const float* src = kv ? vhm : khm;
  const float* pos = kv ? v_pos : k_pos;
  const ushort* WTh = kv ? WcvTh : WckTh;
  const ushort* WTl = kv ? WcvTl : WckTl;
  const float* bias = kv ? bcv : bck;
  float* outp = kv ? cvb : ckb;

  __shared__ ushort Ash[64 * 72], Asl[64 * 72];
  __shared__ ushort Bsh[64 * 72], Bsl[64 * 72];
  int tid = threadIdx.x;
  int lane = tid & 63, wave = tid >> 6;
  int wm = (wave >> 1) * 32, wn = (wave & 1) * 32;
  int q = lane >> 4, l15 = lane & 15;
  int srow = tid >> 2;
  int e0 = (tid & 3) * 16;

  f32x4 acc[2][2];
#pragma unroll
  for (int i = 0; i < 2; i++)
#pragma unroll
    for (int j = 0; j < 2; j++) acc[i][j] = (f32x4){0.f, 0.f, 0.f, 0.f};

  for (int t = 0; t < 16; t++) {
    const float* ar = src + (size_t)h * 65536 + (size_t)(srow * 16 + t) * 64 + e0;
    const float* pr = pos + (size_t)(h * 16 + t) * HD + e0;
    ushort hh[16], hl[16];
#pragma unroll
    for (int u = 0; u < 4; u++) {
      float4 av = *(const float4*)(ar + u * 4);
      float4 pv = *(const float4*)(pr + u * 4);
      float vals[4] = {av.x + pv.x, av.y + pv.y, av.z + pv.z, av.w + pv.w};
#pragma unroll
      for (int e = 0; e < 4; e++) {
        ushort hb = f2b(vals[e]);
        hh[u * 4 + e] = hb;
        hl[u * 4 + e] = f2b(vals[e] - b2f(hb));
      }
    }
    *(int4*)&Ash[srow * 72 + e0]     = *(int4*)&hh[0];
    *(int4*)&Ash[srow * 72 + e0 + 8] = *(int4*)&hh[8];
    *(int4*)&Asl[srow * 72 + e0]     = *(int4*)&hl[0];
    *(int4*)&Asl[srow * 72 + e0 + 8] = *(int4*)&hl[8];
    const ushort* bh = WTh + (size_t)srow * 1024 + t * 64 + e0;
    const ushort* bl = WTl + (size_t)srow * 1024 + t * 64 + e0;
    *(int4*)&Bsh[srow * 72 + e0]     = *(const int4*)bh;
    *(int4*)&Bsh[srow * 72 + e0 + 8] = *(const int4*)(bh + 8);
    *(int4*)&Bsl[srow * 72 + e0]     = *(const int4*)bl;
    *(int4*)&Bsl[srow * 72 + e0 + 8] = *(const int4*)(bl + 8);
    __syncthreads();
#pragma unroll
    for (int sub = 0; sub < 2; sub++) {
      bf16x8 afh[2], afl[2], bfh[2], bfl[2];
#pragma unroll
      for (int ti = 0; ti < 2; ti++) {
        int ar2 = (wm + ti * 16 + l15) * 72 + sub * 32 + q * 8;
        int br2 = (wn + ti * 16 + l15) * 72 + sub * 32 + q * 8;
        afh[ti] = *(const bf16x8*)&Ash[ar2];
        afl[ti] = *(const bf16x8*)&Asl[ar2];
        bfh[ti] = *(const bf16x8*)&Bsh[br2];
        bfl[ti] = *(const bf16x8*)&Bsl[br2];
      }
#pragma unroll
      for (int i = 0; i < 2; i++)
#pragma unroll
        for (int j = 0; j < 2; j++) {
          acc[i][j] = __builtin_amdgcn_mfma_f32_16x16x32_bf16(afh[i], bfh[j],
                                                              acc[i][j], 0, 0, 0);
          acc[i][j] = __builtin_amdgcn_mfma_f32_16x16x32_bf16(afh[i], bfl[j],
                                                              acc[i][j], 0, 0, 0);
          acc[i][j] = __builtin_amdgcn_mfma_f32_16x16x32_bf16(afl[i], bfh[j],
                                                              acc[i][j], 0, 0, 0);
        }
    }
    __syncthreads();
  }

#pragma unroll
  for (int i = 0; i < 2; i++) {
#pragma unroll
    for (int j = 0; j < 2; j++) {
      int d = wn + j * 16 + l15;
      float bv = bias[d];
#pragma unroll
      for (int r = 0; r < 4; r++) {
        int c = wm + i * 16 + q * 4 + r;
        outp[((size_t)h * 64 + c) * 64 + d] = acc[i][j][r] + bv;
      }
    }
  }
}

// ---------- compressed attention + top-8 (standalone, barrier-light) ----------
__global__ void __launch_bounds__(256)
k_cmp(const float* __restrict__ qg, const float* __restrict__ ckb,
      const float* __restrict__ cvb, const float* __restrict__ k_mem,
      const float* __restrict__ v_mem, float* __restrict__ cout,
      int* __restrict__ sel) {
  int h = blockIdx.y, i0 = blockIdx.x * 16;
  int tid = threadIdx.x, lane = tid & 63, w = tid >> 6;
  __shared__ float ckt[64][65];
  __shared__ float cvs[64][65];
  __shared__ float qs[16][64];
  __shared__ float kms[64], vms[64];
  __shared__ float sp[4][64];

#pragma unroll
  for (int r = 0; r < 4; r++) {
    int f = r * 256 + tid;
    int c = f >> 4, d0 = (f & 15) * 4;
    float4 t = *(const float4*)(ckb + ((size_t)h * 64 + c) * 64 + d0);
    ckt[d0][c] = t.x; ckt[d0 + 1][c] = t.y; ckt[d0 + 2][c] = t.z; ckt[d0 + 3][c] = t.w;
    float4 u = *(const float4*)(cvb + ((size_t)h * 64 + c) * 64 + d0);
    cvs[c][d0] = u.x; cvs[c][d0 + 1] = u.y; cvs[c][d0 + 2] = u.z; cvs[c][d0 + 3] = u.w;
  }
  {
    int r = tid >> 4, d0 = (tid & 15) * 4;
    float4 t = *(const float4*)(qg + (size_t)(i0 + r) * DIMM + h * HD + d0);
    qs[r][d0] = t.x; qs[r][d0 + 1] = t.y; qs[r][d0 + 2] = t.z; qs[r][d0 + 3] = t.w;
  }
  if (tid < 64) kms[tid] = k_mem[h * HD + tid];
  else if (tid < 128) vms[tid - 64] = v_mem[h * HD + tid - 64];
  __syncthreads();

  for (int s = 0; s < 4; s++) {
    int ql = w * 4 + s, qi = i0 + ql;
    float dot = 0.f, dm = 0.f;
#pragma unroll 8
    for (int e = 0; e < 64; e++) {
      float qe = qs[ql][e];
      dot = fmaf(qe, ckt[e][lane], dot);
      dm  = fmaf(qe, kms[e], dm);
    }
    bool vis = (lane * BCB + BCB - 1) < qi;
    float sj = vis ? dot * SCALE : NEGV;
    float smem = dm * SCALE;
    float m = wred_max(fmaxf(sj, smem));
    float p = expf(sj - m);
    float pmem = expf(smem - m);
    float l = wred_sum(p) + pmem;
    float inv = 1.f / l;

    float impv = vis ? p : NEGV;
#pragma unroll
    for (int kk = 0; kk < KSEL; kk++) {
      float bv = impv; int bi = lane;
#pragma unroll
      for (int off = 32; off > 0; off >>= 1) {
        float ov = __shfl_xor(bv, off);
        int   oi = __shfl_xor(bi, off);
        if (ov > bv || (ov == bv && oi < bi)) { bv = ov; bi = oi; }
      }
      if (lane == 0) sel[((size_t)h * NTOK + qi) * KSEL + kk] = (bv >= 0.f) ? bi : -1;
      if (lane == bi) impv = NEGV;
    }

    sp[w][lane] = p;
    float od = pmem * vms[lane];
#pragma unroll 8
    for (int j = 0; j < 64; j++) od = fmaf(sp[w][j], cvs[j][lane], od);
    cout[(size_t)qi * DIMM + h * HD + lane] = od * inv;
  }
}

// ---------- sliding window: MFMA flash. block=(h, 64 q rows), wave owns 16 rows ----------
__global__ void __launch_bounds__(256)
k_swin(const float* __restrict__ qg, const float* __restrict__ khm,
       const float* __restrict__ vhm, float* __restrict__ sout) {
  int h = blockIdx.y, i0 = blockIdx.x * 64;
  int tid = threadIdx.x, lane = tid & 63, w = tid >> 6;
  int quad = lane >> 4, l15 = lane & 15;

  __shared__ ushort Kt[64 * 72];
  __shared__ ushort VT[64 * 72];
  __shared__ ushort Qs[64 * 72];
  __shared__ ushort Ps[4][16 * 72];

#pragma unroll
  for (int it = 0; it < 4; it++) {
    int f = it * 256 + tid;
    int r = f >> 4, d0 = (f & 15) * 4;
    float4 t = *(const float4*)(qg + (size_t)(i0 + r) * DIMM + h * HD + d0);
    ushort4 u = {f2b(t.x), f2b(t.y), f2b(t.z), f2b(t.w)};
    *(ushort4*)&Qs[r * 72 + d0] = u;
  }

  int lo = i0 - (WWIN - 1); if (lo < 0) lo = 0;
  int jb_lo = lo >> 6, jb_hi = (i0 + 63) >> 6;

  float mrow[4], lrow[4];
  f32x4 Of[4];
#pragma unroll
  for (int r = 0; r < 4; r++) { mrow[r] = NEGV; lrow[r] = 0.f; }
#pragma unroll
  for (int d = 0; d < 4; d++) Of[d] = (f32x4){0.f, 0.f, 0.f, 0.f};

  for (int jb = jb_lo; jb <= jb_hi; jb++) {
    __syncthreads();
#pragma unroll
    for (int it = 0; it < 4; it++) {
      int f = it * 256 + tid;
      int r = f >> 4, d0 = (f & 15) * 4;
      const float* kp = khm + (size_t)h * 65536 + (size_t)(jb * 64 + r) * 64 + d0;
      float4 t = *(const float4*)kp;
      ushort4 u = {f2b(t.x), f2b(t.y), f2b(t.z), f2b(t.w)};
      *(ushort4*)&Kt[r * 72 + d0] = u;
      const float* vp = vhm + (size_t)h * 65536 + (size_t)(jb * 64 + r) * 64 + d0;
      float4 v4 = *(const float4*)vp;
      VT[(d0    ) * 72 + r] = f2b(v4.x);
      VT[(d0 + 1) * 72 + r] = f2b(v4.y);
      VT[(d0 + 2) * 72 + r] = f2b(v4.z);
      VT[(d0 + 3) * 72 + r] = f2b(v4.w);
    }
    __syncthreads();

    bf16x8 qa[2];
#pragma unroll
    for (int c = 0; c < 2; c++)
      qa[c] = *(const bf16x8*)&Qs[(w * 16 + l15) * 72 + c * 32 + quad * 8];

    f32x4 sc[4];
#pragma unroll
    for (int ks = 0; ks < 4; ks++) {
      f32x4 a = (f32x4){0.f, 0.f, 0.f, 0.f};
#pragma unroll
      for (int c = 0; c < 2; c++) {
        bf16x8 kb = *(const bf16x8*)&Kt[(ks * 16 + l15) * 72 + c * 32 + quad * 8];
        a = __builtin_amdgcn_mfma_f32_16x16x32_bf16(qa[c], kb, a, 0, 0, 0);
      }
      sc[ks] = a;
    }

    float pm[4][4], rmax[4];
#pragma unroll
    for (int r = 0; r < 4; r++) rmax[r] = NEGV;
#pragma unroll
    for (int ks = 0; ks < 4; ks++) {
      int gj = jb * 64 + ks * 16 + l15;
#pragma unroll
      for (int r = 0; r < 4; r++) {
        int qi = i0 + w * 16 + quad * 4 + r;
        bool vis = (gj <= qi) && (qi - gj < WWIN);
        float s = vis ? sc[ks][r] * SCALE : NEGV;
        pm[ks][r] = s;
        rmax[r] = fmaxf(rmax[r], s);
      }
    }
#pragma unroll
    for (int off = 1; off < 16; off <<= 1)
#pragma unroll
      for (int r = 0; r < 4; r++)
        rmax[r] = fmaxf(rmax[r], __shfl_xor(rmax[r], off));

    float alpha[4], rsum[4];
#pragma unroll
    for (int r = 0; r < 4; r++) {
      float newm = fmaxf(mrow[r], rmax[r]);
      alpha[r] = expf(mrow[r] - newm);
      mrow[r] = newm;
      rsum[r] = 0.f;
    }
#pragma unroll
    for (int ks = 0; ks < 4; ks++)
#pragma unroll
      for (int r = 0; r < 4; r++) {
        float p = expf(pm[ks][r] - mrow[r]);
        pm[ks][r] = p;
        rsum[r] += p;
      }
#pragma unroll
    for (int off = 1; off < 16; off <<= 1)
#pragma unroll
      for (int r = 0; r < 4; r++)
        rsum[r] += __shfl_xor(rsum[r], off);
#pragma unroll
    for (int r = 0; r < 4; r++)
      lrow[r] = lrow[r] * alpha[r] + rsum[r];

#pragma unroll
    for (int ks = 0; ks < 4; ks++)
#pragma unroll
      for (int r = 0; r < 4; r++)
        Ps[w][(quad * 4 + r) * 72 + ks * 16 + l15] = f2b(pm[ks][r]);
#pragma unroll
    for (int d = 0; d < 4; d++)
#pragma unroll
      for (int r = 0; r < 4; r++)
        Of[d][r] *= alpha[r];

#pragma unroll
    for (int c = 0; c < 2; c++) {
      bf16x8 pa = *(const bf16x8*)&Ps[w][l15 * 72 + c * 32 + quad * 8];
#pragma unroll
      for (int d = 0; d < 4; d++) {
        bf16x8 vb = *(const bf16x8*)&VT[(d * 16 + l15) * 72 + c * 32 + quad * 8];
        Of[d] = __builtin_amdgcn_mfma_f32_16x16x32_bf16(pa, vb, Of[d], 0, 0, 0);
      }
    }
  }

#pragma unroll
  for (int d = 0; d < 4; d++)
#pragma unroll
    for (int r = 0; r < 4; r++) {
      int qi = i0 + w * 16 + quad * 4 + r;
      sout[(size_t)qi * DIMM + h * HD + d * 16 + l15] = Of[d][r] / lrow[r];
    }
}

// ---------- fine attention: direct QK gather + bf16 V staged in LDS ----------
__global__ void __launch_bounds__(256)
k_fine(const float* __restrict__ qg, const float* __restrict__ khm,
       const float* __restrict__ vhm, const int* __restrict__ sel,
       float* __restrict__ fout) {
  int i = blockIdx.x, h = blockIdx.y;
  int tid = threadIdx.x, lane = tid & 63, w = tid >> 6;
  __shared__ float qsh[64];
  __shared__ ushort vsb[144 * 64];
  __shared__ float sp[144];
  __shared__ int selS[8];
  __shared__ float mred[4], sredS[4];
  __shared__ float pacc[4][64];

  int own = i >> 4;
  if (tid < 64) qsh[tid] = qg[(size_t)i * DIMM + h * HD + tid];
  if (tid >= 64 && tid < 72)
    selS[tid - 64] = sel[((size_t)h * NTOK + i) * KSEL + tid - 64];
  __syncthreads();

  const float* kbase = khm + (size_t)h * 65536;
  const float* vbase = vhm + (size_t)h * 65536;

#pragma unroll
  for (int it = 0; it < 9; it++) {
    int idx = it * 256 + tid;
    int row = idx >> 4, c4 = (idx & 15) * 4;
    int kk = row >> 4;
    int bidx = (kk < KSEL) ? selS[kk] : own;
    if (bidx < 0) bidx = 0;
    float4 t = *(const float4*)(vbase + (size_t)(bidx * BSB + (row & 15)) * 64 + c4);
    ushort4 u = {f2b(t.x), f2b(t.y), f2b(t.z), f2b(t.w)};
    *(ushort4*)&vsb[row * 64 + c4] = u;
  }

  float s_loc = NEGV;
  bool active = (tid < 144);
  if (active) {
    int kk = tid >> 4;
    int bidx; bool vis;
    if (kk < KSEL) {
      bidx = selS[kk];
      vis = (bidx >= 0);
      if (!vis) bidx = 0;
    } else {
      bidx = own;
      vis = (tid - 128) <= (i & 15);
    }
    const float* kr = kbase + (size_t)(bidx * BSB + (tid & 15)) * 64;
    float dot = 0.f;
#pragma unroll
    for (int e4 = 0; e4 < 16; e4++) {
      float4 kv = *(const float4*)(kr + e4 * 4);
      float4 qv = *(const float4*)&qsh[e4 * 4];
      dot = fmaf(qv.x, kv.x, dot); dot = fmaf(qv.y, kv.y, dot);
      dot = fmaf(qv.z, kv.z, dot); dot = fmaf(qv.w, kv.w, dot);
    }
    s_loc = vis ? dot * SCALE : NEGV;
  }
  float mw = wred_max(s_loc);
  if (lane == 0) mred[w] = mw;
  __syncthreads();
  float m = fmaxf(fmaxf(mred[0], mred[1]), fmaxf(mred[2], mred[3]));
  float p = active ? expf(s_loc - m) : 0.f;
  float sw = wred_sum(p);
  if (lane == 0) sredS[w] = sw;
  if (active) sp[tid] = p;
  __syncthreads();
  float l = sredS[0] + sredS[1] + sredS[2] + sredS[3];

  float acc = 0.f;
  int j0 = w * 36;
#pragma unroll 6
  for (int jj = 0; jj < 36; jj++) {
    int j = j0 + jj;
    acc = fmaf(sp[j], b2f(vsb[j * 64 + lane]), acc);
  }
  pacc[w][lane] = acc;
  __syncthreads();
  if (w == 0)
    fout[(size_t)i * DIMM + h * HD + lane] =
        (pacc[0][lane] + pacc[1][lane] + pacc[2][lane] + pacc[3][lane]) / l;
}

extern "C" void kernel_launch(void* const* d_in, const int* in_sizes, int n_in,
                              void* d_out, int out_size, void* d_ws, size_t ws_size,
                              hipStream_t stream) {
  const float* x     = (const float*)d_in[0];
  const float* ve    = (const float*)d_in[1]; (void)ve;
  const float* x0    = (const float*)d_in[2];
  const float* lam   = (const float*)d_in[3];
  const float* Wq    = (const float*)d_in[4];
  const float* Wk    = (const float*)d_in[5];
  const float* Wv    = (const float*)d_in[6];
  const float* Wo    = (const float*)d_in[7];
  const float* Wg    = (const float*)d_in[8];
  const float* k_pos = (const float*)d_in[9];
  const float* v_pos = (const float*)d_in[10];
  const float* Wck   = (const float*)d_in[11];
  const float* bck   = (const float*)d_in[12];
  const float* Wcv   = (const float*)d_in[13];
  const float* bcv   = (const float*)d_in[14];
  const float* k_mem = (const float*)d_in[15];
  const float* v_mem = (const float*)d_in[16];
  const float* W1    = (const float*)d_in[17];
  const float* W2    = (const float*)d_in[18];
  float* out = (float*)d_out;
  float* ws  = (float*)d_ws;

  const size_t NW = (size_t)NTOK * DIMM;   // 524288
  float* xr    = ws;
  float* xn    = ws + 1 * NW;     // later: W2 partial p0
  float* q     = ws + 2 * NW;     // later: h1b (bf16, spans slots 2-3)
  float* k     = ws + 3 * NW;
  float* vhm   = ws + 4 * NW;     // later: W2 partial p1
  float* coutb = ws + 5 * NW;
  float* foutb = ws + 6 * NW;
  float* soutb = ws + 7 * NW;
  float* x2    = ws + 8 * NW;     // khm until gemm_wo overwrites as x2
  float* khm   = x2;
  float* gates = ws + 9 * NW;
  float* ckb   = gates + 32768;
  float* cvb   = ckb + 32768;
  int*   selb  = (int*)(cvb + 32768);
  ushort* qkvTh = (ushort*)(cvb + 32768 + 65536);
  ushort* qkvTl = qkvTh + 1600 * 512;
  ushort* WoT   = qkvTl + 1600 * 512;
  ushort* W1T   = WoT   + 512 * 512;
  ushort* W2T   = W1T   + 2048 * 512;
  ushort* WckTh = W2T   + 512 * 2048;
  ushort* WckTl = WckTh + 64 * 1024;
  ushort* WcvTh = WckTl + 64 * 1024;
  ushort* WcvTl = WcvTh + 64 * 1024;
  ushort* ybf = (ushort*)xr;     // bf16 y, reuse xr after Wo consumed it
  ushort* h1b = (ushort*)q;      // bf16 h1 (1024x2048 = 4MB), slots 2-3
  float* p0 = xn;                // W2 split-K partials (2 MB each)
  float* p1 = vhm;

  WtrPack pk;
  pk.d[0] = {Wq, qkvTh,              qkvTl,              512, 512,  512};
  pk.d[1] = {Wk, qkvTh + 512 * 512,  qkvTl + 512 * 512,  512, 512,  512};
  pk.d[2] = {Wv, qkvTh + 1024 * 512, qkvTl + 1024 * 512, 512, 512,  512};
  pk.d[3] = {Wo, WoT, nullptr,  512, 512,  512};
  pk.d[4] = {W1, W1T, nullptr,  512, 2048, 2048};
  pk.d[5] = {W2, W2T, nullptr, 2048, 512,  512};
  pk.d[6] = {Wck, WckTh, WckTl, 1024, 64, 64};
  pk.d[7] = {Wcv, WcvTh, WcvTl, 1024, 64, 64};
  pk.d[8] = {Wg, qkvTh + 1536 * 512, qkvTl + 1536 * 512, 512, 24, 64};
  int cum = 0;
  for (int e = 0; e < 9; e++) {
    cum += (pk.d[e].Npad / 32) * (pk.d[e].K / 32);
    pk.cum[e] = cum;
  }
  k_wtr_all<<<cum, dim3(32, 8), 0, stream>>>(pk);

  k_resid_rms<<<NTOK, 256, 0, stream>>>(x, x0, lam, xr, xn);

  k_gemm_qkv<<<dim3(25, NTOK / 64), 256, 0, stream>>>(
      xn, qkvTh, qkvTl, q, vhm, gates, 512);
  k_rope<<<(2 * NTOK * NH * 32) / 256, 256, 0, stream>>>(q, k, khm);

  k_ckcv_m<<<dim3(NH, 2), 256, 0, stream>>>(khm, vhm, k_pos, v_pos,
                                            WckTh, WckTl, WcvTh, WcvTl,
                                            bck, bcv, ckb, cvb);
  k_cmp<<<dim3(NTOK / 16, NH), 256, 0, stream>>>(q, ckb, cvb, k_mem, v_mem,
                                                 coutb, selb);
  k_swin<<<dim3(NTOK / 64, NH), 256, 0, stream>>>(q, khm, vhm, soutb);
  k_fine<<<dim3(NTOK, NH), 256, 0, stream>>>(q, khm, vhm, selb, foutb);

  k_gemm_wo<<<dim3(512 / 64, NTOK / 64), 256, 0, stream>>>(
      coutb, foutb, soutb, gates, WoT, xr, x2);

  k_rms_bf<<<NTOK, 256, 0, stream>>>(x2, ybf);
  // W1: 128x64 tiles -> 256 blocks
  k_gemm_w1<<<dim3(2048 / 64, NTOK / 128), 256, 0, stream>>>(ybf, W1T, h1b);
  // W2: 64x64 tiles, split-K=2 -> 256 blocks
  k_gemm_w2<<<dim3(512 / 64, NTOK / 64, 2), 256, 0, stream>>>(h1b, W2T, p0, p1);
  k_w2fin<<<NW / 256, 256, 0, stream>>>(x2, p0, p1, out);
}

// Round 11
// 279.655 us; speedup vs baseline: 1.2775x; 1.0689x over previous
//
#include <hip/hip_runtime.h>
#include <math.h>

#define NTOK 1024
#define DIMM 512
#define NH 8
#define HD 64
#define BCB 16
#define BSB 16
#define KSEL 8
#define WWIN 256
#define CBLK 64
#define SCALE 0.125f
#define EPSV 1e-6f
#define NEGV -1e30f

typedef short bf16x8 __attribute__((ext_vector_type(8)));
typedef float f32x4 __attribute__((ext_vector_type(4)));

__device__ inline ushort f2b(float f) {
  union { float f; unsigned int u; } c; c.f = f;
  unsigned int u = c.u;
  return (ushort)((u + 0x7FFFu + ((u >> 16) & 1u)) >> 16);
}
__device__ inline float b2f(ushort h) {
  union { unsigned int u; float f; } c; c.u = ((unsigned int)h) << 16;
  return c.f;
}

__device__ inline float wred_max(float v) {
#pragma unroll
  for (int off = 1; off < 64; off <<= 1) v = fmaxf(v, __shfl_xor(v, off));
  return v;
}
__device__ inline float wred_sum(float v) {
#pragma unroll
  for (int off = 1; off < 64; off <<= 1) v += __shfl_xor(v, off);
  return v;
}

// ---------- residual mix + rmsnorm ----------
__global__ void __launch_bounds__(256)
k_resid_rms(const float* __restrict__ x, const float* __restrict__ x0,
            const float* __restrict__ lam, float* __restrict__ xr,
            float* __restrict__ xn) {
  int row = blockIdx.x, tid = threadIdx.x;
  float l0 = lam[0], l1 = lam[1];
  size_t b = (size_t)row * DIMM;
  float a0 = l0 * x[b + tid]       + l1 * x0[b + tid];
  float a1 = l0 * x[b + tid + 256] + l1 * x0[b + tid + 256];
  xr[b + tid] = a0; xr[b + tid + 256] = a1;
  float ss = a0 * a0 + a1 * a1;
  __shared__ float sm[8];
  for (int o = 32; o > 0; o >>= 1) ss += __shfl_down(ss, o);
  int lane = tid & 63, wid = tid >> 6;
  if (lane == 0) sm[wid] = ss;
  __syncthreads();
  if (tid == 0) {
    float s = sm[0] + sm[1] + sm[2] + sm[3];
    sm[0] = rsqrtf(s / (float)DIMM + EPSV);
  }
  __syncthreads();
  float r = sm[0];
  xn[b + tid] = a0 * r; xn[b + tid + 256] = a1 * r;
}

// ---------- rmsnorm -> bf16 output ----------
__global__ void __launch_bounds__(256)
k_rms_bf(const float* __restrict__ xin, ushort* __restrict__ y) {
  int row = blockIdx.x, tid = threadIdx.x;
  size_t b = (size_t)row * DIMM;
  float a0 = xin[b + tid], a1 = xin[b + tid + 256];
  float ss = a0 * a0 + a1 * a1;
  __shared__ float sm[8];
  for (int o = 32; o > 0; o >>= 1) ss += __shfl_down(ss, o);
  int lane = tid & 63, wid = tid >> 6;
  if (lane == 0) sm[wid] = ss;
  __syncthreads();
  if (tid == 0) {
    float s = sm[0] + sm[1] + sm[2] + sm[3];
    sm[0] = rsqrtf(s / (float)DIMM + EPSV);
  }
  __syncthreads();
  float r = sm[0];
  y[b + tid] = f2b(a0 * r); y[b + tid + 256] = f2b(a1 * r);
}

// ---------- consolidated weight transposes (f32 K×N -> bf16 hi/lo N×K) ----------
struct WtrDesc { const float* src; ushort* dh; ushort* dl; int K; int Nsrc; int Npad; };
struct WtrPack { WtrDesc d[9]; int cum[9]; };

__global__ void __launch_bounds__(256)
k_wtr_all(WtrPack pk) {
  int gb = blockIdx.x;
  int e = 0;
  while (gb >= pk.cum[e]) e++;
  int start = e ? pk.cum[e - 1] : 0;
  WtrDesc dd = pk.d[e];
  int local = gb - start;
  int XT = dd.Npad >> 5;
  int bx = local % XT, by = local / XT;
  __shared__ float t[32][33];
  int n0 = bx * 32, k0 = by * 32;
  int tx = threadIdx.x, ty = threadIdx.y;  // 32 x 8
#pragma unroll
  for (int i = 0; i < 32; i += 8)
    t[ty + i][tx] = (n0 + tx < dd.Nsrc)
        ? dd.src[(size_t)(k0 + ty + i) * dd.Nsrc + n0 + tx] : 0.f;
  __syncthreads();
#pragma unroll
  for (int i = 0; i < 32; i += 8) {
    float vv = t[tx][ty + i];
    ushort h = f2b(vv);
    size_t di = (size_t)(n0 + ty + i) * dd.K + k0 + tx;
    dd.dh[di] = h;
    if (dd.dl) dd.dl[di] = f2b(vv - b2f(h));
  }
}

// ---------- W1 GEMM: 128Mx64N tile, A bf16, relu^2 -> bf16. grid (32,8) ----------
__global__ void __launch_bounds__(256)
k_gemm_w1(const ushort* __restrict__ A, const ushort* __restrict__ BT,
          ushort* __restrict__ Co) {
  const int Kd = 512, Nd = 2048;
  __shared__ ushort As[128 * 40];
  __shared__ ushort Bs[64 * 40];
  int tid = threadIdx.x;
  int lane = tid & 63, w = tid >> 6;
  int rb = blockIdx.y * 128, cb = blockIdx.x * 64;
  int wm = (w >> 1) * 64, wn = (w & 1) * 32;
  int quad = lane >> 4, l15 = lane & 15;
  int srA = tid >> 1, scA = (tid & 1) * 16;
  int srB = tid >> 2, scB = (tid & 3) * 8;

  f32x4 acc[4][2];
#pragma unroll
  for (int i = 0; i < 4; i++)
#pragma unroll
    for (int j = 0; j < 2; j++) acc[i][j] = (f32x4){0.f, 0.f, 0.f, 0.f};

  const ushort* ap = A  + (size_t)(rb + srA) * Kd + scA;
  const ushort* bp = BT + (size_t)(cb + srB) * Kd + scB;
  ushort* aw = &As[srA * 40 + scA];
  ushort* bw = &Bs[srB * 40 + scB];

  int4 pa0 = *(const int4*)ap;
  int4 pa1 = *(const int4*)(ap + 8);
  int4 pb  = *(const int4*)bp;

  for (int k0 = 0; k0 < Kd; k0 += 32) {
    if (k0) __syncthreads();
    *(int4*)aw = pa0; *(int4*)(aw + 8) = pa1;
    *(int4*)bw = pb;
    __syncthreads();
    if (k0 + 32 < Kd) {
      pa0 = *(const int4*)(ap + k0 + 32);
      pa1 = *(const int4*)(ap + k0 + 40);
      pb  = *(const int4*)(bp + k0 + 32);
    }
    bf16x8 af[4], bfr[2];
#pragma unroll
    for (int t = 0; t < 4; t++)
      af[t] = *(const bf16x8*)&As[(wm + t * 16 + l15) * 40 + quad * 8];
#pragma unroll
    for (int t = 0; t < 2; t++)
      bfr[t] = *(const bf16x8*)&Bs[(wn + t * 16 + l15) * 40 + quad * 8];
#pragma unroll
    for (int i = 0; i < 4; i++)
#pragma unroll
      for (int j = 0; j < 2; j++)
        acc[i][j] = __builtin_amdgcn_mfma_f32_16x16x32_bf16(af[i], bfr[j],
                                                            acc[i][j], 0, 0, 0);
  }

#pragma unroll
  for (int i = 0; i < 4; i++) {
#pragma unroll
    for (int j = 0; j < 2; j++) {
      int col = cb + wn + j * 16 + l15;
#pragma unroll
      for (int r = 0; r < 4; r++) {
        int row = rb + wm + i * 16 + quad * 4 + r;
        float t = fmaxf(acc[i][j][r], 0.f);
        Co[(size_t)row * Nd + col] = f2b(t * t);
      }
    }
  }
}

// ---------- W2 GEMM: 64x64 tile, split-K (z = slice of 1024), f32 partial out ----------
__global__ void __launch_bounds__(256)
k_gemm_w2(const ushort* __restrict__ A, const ushort* __restrict__ BT,
          float* __restrict__ P0, float* __restrict__ P1) {
  const int Kd = 2048;
  __shared__ ushort As[64 * 40];
  __shared__ ushort Bs[64 * 40];
  int tid = threadIdx.x;
  int lane = tid & 63, w = tid >> 6;
  int rb = blockIdx.y * 64, cb = blockIdx.x * 64;
  int kb = blockIdx.z * 1024;
  int wm = (w >> 1) * 32, wn = (w & 1) * 32;
  int quad = lane >> 4, l15 = lane & 15;
  int srow = tid >> 2, scol = (tid & 3) * 8;

  f32x4 acc[2][2];
#pragma unroll
  for (int i = 0; i < 2; i++)
#pragma unroll
    for (int j = 0; j < 2; j++) acc[i][j] = (f32x4){0.f, 0.f, 0.f, 0.f};

  const ushort* ap = A  + (size_t)(rb + srow) * Kd + kb + scol;
  const ushort* bp = BT + (size_t)(cb + srow) * Kd + kb + scol;
  ushort* aw = &As[srow * 40 + scol];
  ushort* bw = &Bs[srow * 40 + scol];

  int4 pa = *(const int4*)ap;
  int4 pb = *(const int4*)bp;

  for (int k0 = 0; k0 < 1024; k0 += 32) {
    if (k0) __syncthreads();
    *(int4*)aw = pa;
    *(int4*)bw = pb;
    __syncthreads();
    if (k0 + 32 < 1024) {
      pa = *(const int4*)(ap + k0 + 32);
      pb = *(const int4*)(bp + k0 + 32);
    }
    bf16x8 af[2], bfr[2];
#pragma unroll
    for (int t = 0; t < 2; t++) {
      af[t]  = *(const bf16x8*)&As[(wm + t * 16 + l15) * 40 + quad * 8];
      bfr[t] = *(const bf16x8*)&Bs[(wn + t * 16 + l15) * 40 + quad * 8];
    }
#pragma unroll
    for (int i = 0; i < 2; i++)
#pragma unroll
      for (int j = 0; j < 2; j++)
        acc[i][j] = __builtin_amdgcn_mfma_f32_16x16x32_bf16(af[i], bfr[j],
                                                            acc[i][j], 0, 0, 0);
  }

  float* pbuf = blockIdx.z ? P1 : P0;
#pragma unroll
  for (int i = 0; i < 2; i++) {
#pragma unroll
    for (int j = 0; j < 2; j++) {
      int col = cb + wn + j * 16 + l15;
#pragma unroll
      for (int r = 0; r < 4; r++) {
        int row = rb + wm + i * 16 + quad * 4 + r;
        pbuf[(size_t)row * 512 + col] = acc[i][j][r];
      }
    }
  }
}

// ---------- W2 finalize: out = x2 + p0 + p1 ----------
__global__ void __launch_bounds__(256)
k_w2fin(const float* __restrict__ x2, const float* __restrict__ p0,
        const float* __restrict__ p1, float* __restrict__ out) {
  int idx = blockIdx.x * 256 + threadIdx.x;
  out[idx] = x2[idx] + p0[idx] + p1[idx];
}

// ---------- Wo GEMM with fused gated combine in A-staging ----------
__global__ void __launch_bounds__(256)
k_gemm_wo(const float* __restrict__ cg, const float* __restrict__ fg,
          const float* __restrict__ sg, const float* __restrict__ gates,
          const ushort* __restrict__ BT, const float* __restrict__ Res,
          float* __restrict__ Co) {
  __shared__ ushort As[64 * 40];
  __shared__ ushort Bs[64 * 40];
  int tid = threadIdx.x;
  int lane = tid & 63, wave = tid >> 6;
  int rb = blockIdx.y * 64, cb = blockIdx.x * 64;
  int wm = (wave >> 1) * 32, wn = (wave & 1) * 32;
  int q = lane >> 4, l15 = lane & 15;
  int srow = tid >> 2, scol = (tid & 3) * 8;

  f32x4 acc[2][2];
#pragma unroll
  for (int i = 0; i < 2; i++)
#pragma unroll
    for (int j = 0; j < 2; j++) acc[i][j] = (f32x4){0.f, 0.f, 0.f, 0.f};

  int row = rb + srow;
  const ushort* bp = BT + (size_t)(cb + srow) * 512 + scol;
  ushort* aw = &As[srow * 40 + scol];
  ushort* bw = &Bs[srow * 40 + scol];

  for (int k0 = 0; k0 < 512; k0 += 32) {
    int colb = k0 + scol;
    int hh = colb >> 6;
    const float* gp = gates + (size_t)row * 24 + hh * 3;
    float g0 = gp[0], g1 = gp[1], g2 = gp[2];
    size_t off = (size_t)row * 512 + colb;
    float4 c0 = *(const float4*)(cg + off), c1 = *(const float4*)(cg + off + 4);
    float4 f0 = *(const float4*)(fg + off), f1 = *(const float4*)(fg + off + 4);
    float4 s0 = *(const float4*)(sg + off), s1 = *(const float4*)(sg + off + 4);
    float va[8] = {g0 * c0.x + g1 * f0.x + g2 * s0.x,
                   g0 * c0.y + g1 * f0.y + g2 * s0.y,
                   g0 * c0.z + g1 * f0.z + g2 * s0.z,
                   g0 * c0.w + g1 * f0.w + g2 * s0.w,
                   g0 * c1.x + g1 * f1.x + g2 * s1.x,
                   g0 * c1.y + g1 * f1.y + g2 * s1.y,
                   g0 * c1.z + g1 * f1.z + g2 * s1.z,
                   g0 * c1.w + g1 * f1.w + g2 * s1.w};
    ushort h[8];
#pragma unroll
    for (int e = 0; e < 8; e++) h[e] = f2b(va[e]);
    *(int4*)aw = *(int4*)h;
    *(int4*)bw = *(const int4*)(bp + k0);
    __syncthreads();
    bf16x8 af[2], bfr[2];
#pragma unroll
    for (int t = 0; t < 2; t++) {
      af[t]  = *(const bf16x8*)&As[(wm + t * 16 + l15) * 40 + q * 8];
      bfr[t] = *(const bf16x8*)&Bs[(wn + t * 16 + l15) * 40 + q * 8];
    }
#pragma unroll
    for (int i = 0; i < 2; i++)
#pragma unroll
      for (int j = 0; j < 2; j++)
        acc[i][j] = __builtin_amdgcn_mfma_f32_16x16x32_bf16(af[i], bfr[j],
                                                            acc[i][j], 0, 0, 0);
    __syncthreads();
  }

#pragma unroll
  for (int i = 0; i < 2; i++) {
#pragma unroll
    for (int j = 0; j < 2; j++) {
      int col = cb + wn + j * 16 + l15;
#pragma unroll
      for (int r = 0; r < 4; r++) {
        int rr = rb + wm + i * 16 + q * 4 + r;
        Co[(size_t)rr * 512 + col] = acc[i][j][r] + Res[(size_t)rr * 512 + col];
      }
    }
  }
}

// ---------- split-bf16 MFMA GEMM (hi+lo): QKV + gates; v written head-major ----------
__global__ void __launch_bounds__(256)
k_gemm_qkv(const float* __restrict__ A, const ushort* __restrict__ BTh,
           const ushort* __restrict__ BTl, float* __restrict__ Co,
           float* __restrict__ vhm, float* __restrict__ gates, int Kd) {
  __shared__ ushort Ash[64 * 40];
  __shared__ ushort Asl[64 * 40];
  __shared__ ushort Bsh[64 * 40];
  __shared__ ushort Bsl[64 * 40];
  int tid = threadIdx.x;
  int lane = tid & 63, wave = tid >> 6;
  int rb = blockIdx.y * 64, cb = blockIdx.x * 64;
  int wm = (wave >> 1) * 32, wn = (wave & 1) * 32;
  int q = lane >> 4, l15 = lane & 15;
  int srow = tid >> 2, scol = (tid & 3) * 8;

  f32x4 acc[2][2];
#pragma unroll
  for (int i = 0; i < 2; i++)
#pragma unroll
    for (int j = 0; j < 2; j++) acc[i][j] = (f32x4){0.f, 0.f, 0.f, 0.f};

  const float*  ap  = A   + (size_t)(rb + srow) * Kd + scol;
  const ushort* bph = BTh + (size_t)(cb + srow) * Kd + scol;
  const ushort* bpl = BTl + (size_t)(cb + srow) * Kd + scol;
  ushort* awh = &Ash[srow * 40 + scol];
  ushort* awl = &Asl[srow * 40 + scol];
  ushort* bwh = &Bsh[srow * 40 + scol];
  ushort* bwl = &Bsl[srow * 40 + scol];

  for (int k0 = 0; k0 < Kd; k0 += 32) {
    float4 a0 = *(const float4*)(ap + k0);
    float4 a1 = *(const float4*)(ap + k0 + 4);
    float va[8] = {a0.x, a0.y, a0.z, a0.w, a1.x, a1.y, a1.z, a1.w};
    ushort hh[8], hl[8];
#pragma unroll
    for (int e = 0; e < 8; e++) {
      hh[e] = f2b(va[e]);
      hl[e] = f2b(va[e] - b2f(hh[e]));
    }
    *(int4*)awh = *(int4*)hh;
    *(int4*)awl = *(int4*)hl;
    *(int4*)bwh = *(const int4*)(bph + k0);
    *(int4*)bwl = *(const int4*)(bpl + k0);
    __syncthreads();
    bf16x8 afh[2], afl[2], bfh[2], bfl[2];
#pragma unroll
    for (int t = 0; t < 2; t++) {
      int ar = (wm + t * 16 + l15) * 40 + q * 8;
      int br = (wn + t * 16 + l15) * 40 + q * 8;
      afh[t] = *(const bf16x8*)&Ash[ar];
      afl[t] = *(const bf16x8*)&Asl[ar];
      bfh[t] = *(const bf16x8*)&Bsh[br];
      bfl[t] = *(const bf16x8*)&Bsl[br];
    }
#pragma unroll
    for (int i = 0; i < 2; i++)
#pragma unroll
      for (int j = 0; j < 2; j++) {
        acc[i][j] = __builtin_amdgcn_mfma_f32_16x16x32_bf16(afh[i], bfh[j],
                                                            acc[i][j], 0, 0, 0);
        acc[i][j] = __builtin_amdgcn_mfma_f32_16x16x32_bf16(afh[i], bfl[j],
                                                            acc[i][j], 0, 0, 0);
        acc[i][j] = __builtin_amdgcn_mfma_f32_16x16x32_bf16(afl[i], bfh[j],
                                                            acc[i][j], 0, 0, 0);
      }
    __syncthreads();
  }

  const size_t NW = (size_t)NTOK * DIMM;
#pragma unroll
  for (int i = 0; i < 2; i++) {
#pragma unroll
    for (int j = 0; j < 2; j++) {
      int col = cb + wn + j * 16 + l15;
#pragma unroll
      for (int r = 0; r < 4; r++) {
        int row = rb + wm + i * 16 + q * 4 + r;
        float vv = acc[i][j][r];
        if (cb >= 1536) {
          int c24 = col - 1536;
          if (c24 < 24)
            gates[(size_t)row * 24 + c24] = 1.f / (1.f + expf(-vv));
        } else if (col >= 1024) {
          int c = col - 1024;   // v plane -> head-major
          vhm[(size_t)(c >> 6) * 65536 + (size_t)row * 64 + (c & 63)] = vv;
        } else {
          Co[(size_t)(col >> 9) * NW + (size_t)row * 512 + (col & 511)] = vv;
        }
      }
    }
  }
}

// ---------- RoPE: q in-place; k -> khm f32 + khm_bf bf16; vhm -> vhm_bf ----------
__global__ void __launch_bounds__(256)
k_rope(float* __restrict__ q, const float* __restrict__ k,
       float* __restrict__ khm, ushort* __restrict__ khm_bf,
       const float* __restrict__ vhm, ushort* __restrict__ vhm_bf) {
  int idx = blockIdx.x * 256 + threadIdx.x;
  int seg = idx >> 18;
  if (seg >= 2) {
    int ci = idx - 524288;          // 0..131071, 4 floats each
    if (ci < 131072) {
      float4 t = *(const float4*)(vhm + (size_t)ci * 4);
      ushort4 u = {f2b(t.x), f2b(t.y), f2b(t.z), f2b(t.w)};
      *(ushort4*)(vhm_bf + (size_t)ci * 4) = u;
    }
    return;
  }
  int r = idx & 262143;
  int j = r & 31;
  int h = (r >> 5) & 7;
  int n = r >> 8;
  float inv = powf(10000.f, -(float)j / 32.f);
  float ang = (float)n * inv;
  float sn, cs;
  sincosf(ang, &sn, &cs);
  size_t base = (size_t)n * DIMM + h * HD + j;
  if (seg == 0) {
    float x1 = q[base], x2 = q[base + 32];
    q[base] = x1 * cs - x2 * sn;
    q[base + 32] = x2 * cs + x1 * sn;
  } else {
    float x1 = k[base], x2 = k[base + 32];
    float o1 = x1 * cs - x2 * sn;
    float o2 = x2 * cs + x1 * sn;
    size_t ob = (size_t)h * 65536 + (size_t)n * 64 + j;
    khm[ob] = o1;
    khm[ob + 32] = o2;
    khm_bf[ob] = f2b(o1);
    khm_bf[ob + 32] = f2b(o2);
  }
}

// ---------- compressed k/v via MFMA hi/lo (f32 head-major inputs) ----------
__global__ void __launch_bounds__(256)
k_ckcv_m(const float* __restrict__ khm, const float* __restrict__ vhm,
         const float* __restrict__ k_pos, const float* __restrict__ v_pos,
         const ushort* __restrict__ WckTh, const ushort* __restrict__ WckTl,
         const ushort* __restrict__ WcvTh, const ushort* __restrict__ WcvTl,
         const float* __restrict__ bck, const float* __restrict__ bcv,
         float* __restrict__ ckb, float* __restrict__ cvb) {
  int h = blockIdx.x, kv = blockIdx.y;
  const float* src = kv ? vhm : khm;
  const float* pos = kv ? v_pos : k_pos;
  const ushort* WTh = kv ? WcvTh : WckTh;
  const ushort* WTl = kv ? WcvTl : WckTl;
  const float* bias = kv ? bcv : bck;
  float* outp = kv ? cvb : ckb;

  __shared__ ushort Ash[64 * 72], Asl[64 * 72];
  __shared__ ushort Bsh[64 * 72], Bsl[64 * 72];
  int tid = threadIdx.x;
  int lane = tid & 63, wave = tid >> 6;
  int wm = (wave >> 1) * 32, wn = (wave & 1) * 32;
  int q = lane >> 4, l15 = lane & 15;
  int srow = tid >> 2;
  int e0 = (tid & 3) * 16;

  f32x4 acc[2][2];
#pragma unroll
  for (int i = 0; i < 2; i++)
#pragma unroll
    for (int j = 0; j < 2; j++) acc[i][j] = (f32x4){0.f, 0.f, 0.f, 0.f};

  for (int t = 0; t < 16; t++) {
    const float* ar = src + (size_t)h * 65536 + (size_t)(srow * 16 + t) * 64 + e0;
    const float* pr = pos + (size_t)(h * 16 + t) * HD + e0;
    ushort hh[16], hl[16];
#pragma unroll
    for (int u = 0; u < 4; u++) {
      float4 av = *(const float4*)(ar + u * 4);
      float4 pv = *(const float4*)(pr + u * 4);
      float vals[4] = {av.x + pv.x, av.y + pv.y, av.z + pv.z, av.w + pv.w};
#pragma unroll
      for (int e = 0; e < 4; e++) {
        ushort hb = f2b(vals[e]);
        hh[u * 4 + e] = hb;
        hl[u * 4 + e] = f2b(vals[e] - b2f(hb));
      }
    }
    *(int4*)&Ash[srow * 72 + e0]     = *(int4*)&hh[0];
    *(int4*)&Ash[srow * 72 + e0 + 8] = *(int4*)&hh[8];
    *(int4*)&Asl[srow * 72 + e0]     = *(int4*)&hl[0];
    *(int4*)&Asl[srow * 72 + e0 + 8] = *(int4*)&hl[8];
    const ushort* bh = WTh + (size_t)srow * 1024 + t * 64 + e0;
    const ushort* bl = WTl + (size_t)srow * 1024 + t * 64 + e0;
    *(int4*)&Bsh[srow * 72 + e0]     = *(const int4*)bh;
    *(int4*)&Bsh[srow * 72 + e0 + 8] = *(const int4*)(bh + 8);
    *(int4*)&Bsl[srow * 72 + e0]     = *(const int4*)bl;
    *(int4*)&Bsl[srow * 72 + e0 + 8] = *(const int4*)(bl + 8);
    __syncthreads();
#pragma unroll
    for (int sub = 0; sub < 2; sub++) {
      bf16x8 afh[2], afl[2], bfh[2], bfl[2];
#pragma unroll
      for (int ti = 0; ti < 2; ti++) {
        int ar2 = (wm + ti * 16 + l15) * 72 + sub * 32 + q * 8;
        int br2 = (wn + ti * 16 + l15) * 72 + sub * 32 + q * 8;
        afh[ti] = *(const bf16x8*)&Ash[ar2];
        afl[ti] = *(const bf16x8*)&Asl[ar2];
        bfh[ti] = *(const bf16x8*)&Bsh[br2];
        bfl[ti] = *(const bf16x8*)&Bsl[br2];
      }
#pragma unroll
      for (int i = 0; i < 2; i++)
#pragma unroll
        for (int j = 0; j < 2; j++) {
          acc[i][j] = __builtin_amdgcn_mfma_f32_16x16x32_bf16(afh[i], bfh[j],
                                                              acc[i][j], 0, 0, 0);
          acc[i][j] = __builtin_amdgcn_mfma_f32_16x16x32_bf16(afh[i], bfl[j],
                                                              acc[i][j], 0, 0, 0);
          acc[i][j] = __builtin_amdgcn_mfma_f32_16x16x32_bf16(afl[i], bfh[j],
                                                              acc[i][j], 0, 0, 0);
        }
    }
    __syncthreads();
  }

#pragma unroll
  for (int i = 0; i < 2; i++) {
#pragma unroll
    for (int j = 0; j < 2; j++) {
      int d = wn + j * 16 + l15;
      float bv = bias[d];
#pragma unroll
      for (int r = 0; r < 4; r++) {
        int c = wm + i * 16 + q * 4 + r;
        outp[((size_t)h * 64 + c) * 64 + d] = acc[i][j][r] + bv;
      }
    }
  }
}

// ---------- compressed attention + top-8 (f32 path — selection-critical) ----------
__global__ void __launch_bounds__(256)
k_cmp(const float* __restrict__ qg, const float* __restrict__ ckb,
      const float* __restrict__ cvb, const float* __restrict__ k_mem,
      const float* __restrict__ v_mem, float* __restrict__ cout,
      int* __restrict__ sel) {
  int h = blockIdx.y, i0 = blockIdx.x * 16;
  int tid = threadIdx.x, lane = tid & 63, w = tid >> 6;
  __shared__ float ckt[64][65];
  __shared__ float cvs[64][65];
  __shared__ float qs[16][64];
  __shared__ float kms[64], vms[64];
  __shared__ float sp[4][64];

#pragma unroll
  for (int r = 0; r < 4; r++) {
    int f = r * 256 + tid;
    int c = f >> 4, d0 = (f & 15) * 4;
    float4 t = *(const float4*)(ckb + ((size_t)h * 64 + c) * 64 + d0);
    ckt[d0][c] = t.x; ckt[d0 + 1][c] = t.y; ckt[d0 + 2][c] = t.z; ckt[d0 + 3][c] = t.w;
    float4 u = *(const float4*)(cvb + ((size_t)h * 64 + c) * 64 + d0);
    cvs[c][d0] = u.x; cvs[c][d0 + 1] = u.y; cvs[c][d0 + 2] = u.z; cvs[c][d0 + 3] = u.w;
  }
  {
    int r = tid >> 4, d0 = (tid & 15) * 4;
    float4 t = *(const float4*)(qg + (size_t)(i0 + r) * DIMM + h * HD + d0);
    qs[r][d0] = t.x; qs[r][d0 + 1] = t.y; qs[r][d0 + 2] = t.z; qs[r][d0 + 3] = t.w;
  }
  if (tid < 64) kms[tid] = k_mem[h * HD + tid];
  else if (tid < 128) vms[tid - 64] = v_mem[h * HD + tid - 64];
  __syncthreads();

  for (int s = 0; s < 4; s++) {
    int ql = w * 4 + s, qi = i0 + ql;
    float dot = 0.f, dm = 0.f;
#pragma unroll 8
    for (int e = 0; e < 64; e++) {
      float qe = qs[ql][e];
      dot = fmaf(qe, ckt[e][lane], dot);
      dm  = fmaf(qe, kms[e], dm);
    }
    bool vis = (lane * BCB + BCB - 1) < qi;
    float sj = vis ? dot * SCALE : NEGV;
    float smem = dm * SCALE;
    float m = wred_max(fmaxf(sj, smem));
    float p = expf(sj - m);
    float pmem = expf(smem - m);
    float l = wred_sum(p) + pmem;
    float inv = 1.f / l;

    float impv = vis ? p : NEGV;
#pragma unroll
    for (int kk = 0; kk < KSEL; kk++) {
      float bv = impv; int bi = lane;
#pragma unroll
      for (int off = 32; off > 0; off >>= 1) {
        float ov = __shfl_xor(bv, off);
        int   oi = __shfl_xor(bi, off);
        if (ov > bv || (ov == bv && oi < bi)) { bv = ov; bi = oi; }
      }
      if (lane == 0) sel[((size_t)h * NTOK + qi) * KSEL + kk] = (bv >= 0.f) ? bi : -1;
      if (lane == bi) impv = NEGV;
    }

    sp[w][lane] = p;
    float od = pmem * vms[lane];
#pragma unroll 8
    for (int j = 0; j < 64; j++) od = fmaf(sp[w][j], cvs[j][lane], od);
    cout[(size_t)qi * DIMM + h * HD + lane] = od * inv;
  }
}

// ---------- sliding window: MFMA flash, bf16 K/V mirrors ----------
__global__ void __launch_bounds__(256)
k_swin(const float* __restrict__ qg, const ushort* __restrict__ khm_bf,
       const ushort* __restrict__ vhm_bf, float* __restrict__ sout) {
  int h = blockIdx.y, i0 = blockIdx.x * 64;
  int tid = threadIdx.x, lane = tid & 63, w = tid >> 6;
  int quad = lane >> 4, l15 = lane & 15;

  __shared__ ushort Kt[64 * 72];
  __shared__ ushort VT[64 * 72];
  __shared__ ushort Qs[64 * 72];
  __shared__ ushort Ps[4][16 * 72];

#pragma unroll
  for (int it = 0; it < 4; it++) {
    int f = it * 256 + tid;
    int r = f >> 4, d0 = (f & 15) * 4;
    float4 t = *(const float4*)(qg + (size_t)(i0 + r) * DIMM + h * HD + d0);
    ushort4 u = {f2b(t.x), f2b(t.y), f2b(t.z), f2b(t.w)};
    *(ushort4*)&Qs[r * 72 + d0] = u;
  }

  int lo = i0 - (WWIN - 1); if (lo < 0) lo = 0;
  int jb_lo = lo >> 6, jb_hi = (i0 + 63) >> 6;

  float mrow[4], lrow[4];
  f32x4 Of[4];
#pragma unroll
  for (int r = 0; r < 4; r++) { mrow[r] = NEGV; lrow[r] = 0.f; }
#pragma unroll
  for (int d = 0; d < 4; d++) Of[d] = (f32x4){0.f, 0.f, 0.f, 0.f};

  for (int jb = jb_lo; jb <= jb_hi; jb++) {
    __syncthreads();
#pragma unroll
    for (int it = 0; it < 2; it++) {
      int f = it * 256 + tid;          // 512 int4 chunks (8 ushorts each)
      int r = f >> 3, c8 = (f & 7) * 8;
      const ushort* kp = khm_bf + (size_t)h * 65536 + (size_t)(jb * 64 + r) * 64 + c8;
      *(int4*)&Kt[r * 72 + c8] = *(const int4*)kp;
      const ushort* vp = vhm_bf + (size_t)h * 65536 + (size_t)(jb * 64 + r) * 64 + c8;
      ushort vv[8];
      *(int4*)vv = *(const int4*)vp;
#pragma unroll
      for (int e = 0; e < 8; e++) VT[(c8 + e) * 72 + r] = vv[e];
    }
    __syncthreads();

    bf16x8 qa[2];
#pragma unroll
    for (int c = 0; c < 2; c++)
      qa[c] = *(const bf16x8*)&Qs[(w * 16 + l15) * 72 + c * 32 + quad * 8];

    f32x4 sc[4];
#pragma unroll
    for (int ks = 0; ks < 4; ks++) {
      f32x4 a = (f32x4){0.f, 0.f, 0.f, 0.f};
#pragma unroll
      for (int c = 0; c < 2; c++) {
        bf16x8 kb = *(const bf16x8*)&Kt[(ks * 16 + l15) * 72 + c * 32 + quad * 8];
        a = __builtin_amdgcn_mfma_f32_16x16x32_bf16(qa[c], kb, a, 0, 0, 0);
      }
      sc[ks] = a;
    }

    float pm[4][4], rmax[4];
#pragma unroll
    for (int r = 0; r < 4; r++) rmax[r] = NEGV;
#pragma unroll
    for (int ks = 0; ks < 4; ks++) {
      int gj = jb * 64 + ks * 16 + l15;
#pragma unroll
      for (int r = 0; r < 4; r++) {
        int qi = i0 + w * 16 + quad * 4 + r;
        bool vis = (gj <= qi) && (qi - gj < WWIN);
        float s = vis ? sc[ks][r] * SCALE : NEGV;
        pm[ks][r] = s;
        rmax[r] = fmaxf(rmax[r], s);
      }
    }
#pragma unroll
    for (int off = 1; off < 16; off <<= 1)
#pragma unroll
      for (int r = 0; r < 4; r++)
        rmax[r] = fmaxf(rmax[r], __shfl_xor(rmax[r], off));

    float alpha[4], rsum[4];
#pragma unroll
    for (int r = 0; r < 4; r++) {
      float newm = fmaxf(mrow[r], rmax[r]);
      alpha[r] = expf(mrow[r] - newm);
      mrow[r] = newm;
      rsum[r] = 0.f;
    }
#pragma unroll
    for (int ks = 0; ks < 4; ks++)
#pragma unroll
      for (int r = 0; r < 4; r++) {
        float p = expf(pm[ks][r] - mrow[r]);
        pm[ks][r] = p;
        rsum[r] += p;
      }
#pragma unroll
    for (int off = 1; off < 16; off <<= 1)
#pragma unroll
      for (int r = 0; r < 4; r++)
        rsum[r] += __shfl_xor(rsum[r], off);
#pragma unroll
    for (int r = 0; r < 4; r++)
      lrow[r] = lrow[r] * alpha[r] + rsum[r];

#pragma unroll
    for (int ks = 0; ks < 4; ks++)
#pragma unroll
      for (int r = 0; r < 4; r++)
        Ps[w][(quad * 4 + r) * 72 + ks * 16 + l15] = f2b(pm[ks][r]);
#pragma unroll
    for (int d = 0; d < 4; d++)
#pragma unroll
      for (int r = 0; r < 4; r++)
        Of[d][r] *= alpha[r];

#pragma unroll
    for (int c = 0; c < 2; c++) {
      bf16x8 pa = *(const bf16x8*)&Ps[w][l15 * 72 + c * 32 + quad * 8];
#pragma unroll
      for (int d = 0; d < 4; d++) {
        bf16x8 vb = *(const bf16x8*)&VT[(d * 16 + l15) * 72 + c * 32 + quad * 8];
        Of[d] = __builtin_amdgcn_mfma_f32_16x16x32_bf16(pa, vb, Of[d], 0, 0, 0);
      }
    }
  }

#pragma unroll
  for (int d = 0; d < 4; d++)
#pragma unroll
    for (int r = 0; r < 4; r++) {
      int qi = i0 + w * 16 + quad * 4 + r;
      sout[(size_t)qi * DIMM + h * HD + d * 16 + l15] = Of[d][r] / lrow[r];
    }
}

// ---------- fine attention: bf16 K/V mirrors (gather bytes halved) ----------
__global__ void __launch_bounds__(256)
k_fine(const float* __restrict__ qg, const ushort* __restrict__ khm_bf,
       const ushort* __restrict__ vhm_bf, const int* __restrict__ sel,
       float* __restrict__ fout) {
  int i = blockIdx.x, h = blockIdx.y;
  int tid = threadIdx.x, lane = tid & 63, w = tid >> 6;
  __shared__ float qsh[64];
  __shared__ ushort vsb[144 * 64];
  __shared__ float sp[144];
  __shared__ int selS[8];
  __shared__ float mred[4], sredS[4];
  __shared__ float pacc[4][64];

  int own = i >> 4;
  if (tid < 64) qsh[tid] = qg[(size_t)i * DIMM + h * HD + tid];
  if (tid >= 64 && tid < 72)
    selS[tid - 64] = sel[((size_t)h * NTOK + i) * KSEL + tid - 64];
  __syncthreads();

  const ushort* kbase = khm_bf + (size_t)h * 65536;
  const ushort* vbase = vhm_bf + (size_t)h * 65536;

  // stage v rows (bf16, direct copy): 144 rows x 8 int4-chunks = 1152
#pragma unroll
  for (int it = 0; it < 5; it++) {
    int idx = it * 256 + tid;
    if (idx < 1152) {
      int row = idx >> 3, c8 = (idx & 7) * 8;
      int kk = row >> 4;
      int bidx = (kk < KSEL) ? selS[kk] : own;
      if (bidx < 0) bidx = 0;
      *(int4*)&vsb[row * 64 + c8] =
          *(const int4*)(vbase + (size_t)(bidx * BSB + (row & 15)) * 64 + c8);
    }
  }

  float s_loc = NEGV;
  bool active = (tid < 144);
  if (active) {
    int kk = tid >> 4;
    int bidx; bool vis;
    if (kk < KSEL) {
      bidx = selS[kk];
      vis = (bidx >= 0);
      if (!vis) bidx = 0;
    } else {
      bidx = own;
      vis = (tid - 128) <= (i & 15);
    }
    const ushort* kr = kbase + (size_t)(bidx * BSB + (tid & 15)) * 64;
    float dot = 0.f;
#pragma unroll
    for (int e8 = 0; e8 < 8; e8++) {
      ushort kv[8];
      *(int4*)kv = *(const int4*)(kr + e8 * 8);
#pragma unroll
      for (int e = 0; e < 8; e++)
        dot = fmaf(qsh[e8 * 8 + e], b2f(kv[e]), dot);
    }
    s_loc = vis ? dot * SCALE : NEGV;
  }
  float mw = wred_max(s_loc);
  if (lane == 0) mred[w] = mw;
  __syncthreads();
  float m = fmaxf(fmaxf(mred[0], mred[1]), fmaxf(mred[2], mred[3]));
  float p = active ? expf(s_loc - m) : 0.f;
  float sw = wred_sum(p);
  if (lane == 0) sredS[w] = sw;
  if (active) sp[tid] = p;
  __syncthreads();
  float l = sredS[0] + sredS[1] + sredS[2] + sredS[3];

  float acc = 0.f;
  int j0 = w * 36;
#pragma unroll 6
  for (int jj = 0; jj < 36; jj++) {
    int j = j0 + jj;
    acc = fmaf(sp[j], b2f(vsb[j * 64 + lane]), acc);
  }
  pacc[w][lane] = acc;
  __syncthreads();
  if (w == 0)
    fout[(size_t)i * DIMM + h * HD + lane] =
        (pacc[0][lane] + pacc[1][lane] + pacc[2][lane] + pacc[3][lane]) / l;
}

extern "C" void kernel_launch(void* const* d_in, const int* in_sizes, int n_in,
                              void* d_out, int out_size, void* d_ws, size_t ws_size,
                              hipStream_t stream) {
  const float* x     = (const float*)d_in[0];
  const float* ve    = (const float*)d_in[1]; (void)ve;
  const float* x0    = (const float*)d_in[2];
  const float* lam   = (const float*)d_in[3];
  const float* Wq    = (const float*)d_in[4];
  const float* Wk    = (const float*)d_in[5];
  const float* Wv    = (const float*)d_in[6];
  const float* Wo    = (const float*)d_in[7];
  const float* Wg    = (const float*)d_in[8];
  const float* k_pos = (const float*)d_in[9];
  const float* v_pos = (const float*)d_in[10];
  const float* Wck   = (const float*)d_in[11];
  const float* bck   = (const float*)d_in[12];
  const float* Wcv   = (const float*)d_in[13];
  const float* bcv   = (const float*)d_in[14];
  const float* k_mem = (const float*)d_in[15];
  const float* v_mem = (const float*)d_in[16];
  const float* W1    = (const float*)d_in[17];
  const float* W2    = (const float*)d_in[18];
  float* out = (float*)d_out;
  float* ws  = (float*)d_ws;

  const size_t NW = (size_t)NTOK * DIMM;   // 524288
  float* xr    = ws;
  float* xn    = ws + 1 * NW;     // after qkv: khm_bf+vhm_bf mirrors; later W2 p0
  float* q     = ws + 2 * NW;     // later: h1b (bf16, spans slots 2-3)
  float* k     = ws + 3 * NW;     // token-major k (dead after rope)
  float* vhm   = ws + 4 * NW;     // head-major v f32; later W2 p1
  float* coutb = ws + 5 * NW;
  float* foutb = ws + 6 * NW;
  float* soutb = ws + 7 * NW;
  float* x2    = ws + 8 * NW;     // khm f32 until gemm_wo overwrites as x2
  float* khm   = x2;
  float* gates = ws + 9 * NW;
  float* ckb   = gates + 32768;
  float* cvb   = ckb + 32768;
  int*   selb  = (int*)(cvb + 32768);
  ushort* qkvTh = (ushort*)(cvb + 32768 + 65536);
  ushort* qkvTl = qkvTh + 1600 * 512;
  ushort* WoT   = qkvTl + 1600 * 512;
  ushort* W1T   = WoT   + 512 * 512;
  ushort* W2T   = W1T   + 2048 * 512;
  ushort* WckTh = W2T   + 512 * 2048;
  ushort* WckTl = WckTh + 64 * 1024;
  ushort* WcvTh = WckTl + 64 * 1024;
  ushort* WcvTl = WcvTh + 64 * 1024;
  ushort* ybf = (ushort*)xr;      // bf16 y, reuse xr after Wo consumed it
  ushort* h1b = (ushort*)q;       // bf16 h1 (1024x2048 = 4MB), slots 2-3
  float* p0 = xn;                 // W2 split-K partials (2 MB each)
  float* p1 = vhm;
  ushort* khm_bf = (ushort*)xn;            // 1 MB (xn dead after qkv)
  ushort* vhm_bf = khm_bf + 524288;        // 1 MB

  WtrPack pk;
  pk.d[0] = {Wq, qkvTh,              qkvTl,              512, 512,  512};
  pk.d[1] = {Wk, qkvTh + 512 * 512,  qkvTl + 512 * 512,  512, 512,  512};
  pk.d[2] = {Wv, qkvTh + 1024 * 512, qkvTl + 1024 * 512, 512, 512,  512};
  pk.d[3] = {Wo, WoT, nullptr,  512, 512,  512};
  pk.d[4] = {W1, W1T, nullptr,  512, 2048, 2048};
  pk.d[5] = {W2, W2T, nullptr, 2048, 512,  512};
  pk.d[6] = {Wck, WckTh, WckTl, 1024, 64, 64};
  pk.d[7] = {Wcv, WcvTh, WcvTl, 1024, 64, 64};
  pk.d[8] = {Wg, qkvTh + 1536 * 512, qkvTl + 1536 * 512, 512, 24, 64};
  int cum = 0;
  for (int e = 0; e < 9; e++) {
    cum += (pk.d[e].Npad / 32) * (pk.d[e].K / 32);
    pk.cum[e] = cum;
  }
  k_wtr_all<<<cum, dim3(32, 8), 0, stream>>>(pk);

  k_resid_rms<<<NTOK, 256, 0, stream>>>(x, x0, lam, xr, xn);

  k_gemm_qkv<<<dim3(25, NTOK / 64), 256, 0, stream>>>(
      xn, qkvTh, qkvTl, q, vhm, gates, 512);
  // rope: q(seg0), k->khm+khm_bf(seg1), vhm->vhm_bf(seg2)
  k_rope<<<2560, 256, 0, stream>>>(q, k, khm, khm_bf, vhm, vhm_bf);

  k_ckcv_m<<<dim3(NH, 2), 256, 0, stream>>>(khm, vhm, k_pos, v_pos,
                                            WckTh, WckTl, WcvTh, WcvTl,
                                            bck, bcv, ckb, cvb);
  k_cmp<<<dim3(NTOK / 16, NH), 256, 0, stream>>>(q, ckb, cvb, k_mem, v_mem,
                                                 coutb, selb);
  k_swin<<<dim3(NTOK / 64, NH), 256, 0, stream>>>(q, khm_bf, vhm_bf, soutb);
  k_fine<<<dim3(NTOK, NH), 256, 0, stream>>>(q, khm_bf, vhm_bf, selb, foutb);

  k_gemm_wo<<<dim3(512 / 64, NTOK / 64), 256, 0, stream>>>(
      coutb, foutb, soutb, gates, WoT, xr, x2);

  k_rms_bf<<<NTOK, 256, 0, stream>>>(x2, ybf);
  k_gemm_w1<<<dim3(2048 / 64, NTOK / 128), 256, 0, stream>>>(ybf, W1T, h1b);
  k_gemm_w2<<<dim3(512 / 64, NTOK / 64, 2), 256, 0, stream>>>(h1b, W2T, p0, p1);
  k_w2fin<<<NW / 256, 256, 0, stream>>>(x2, p0, p1, out);
}

// Round 12
// 270.101 us; speedup vs baseline: 1.3227x; 1.0354x over previous
//
#include <hip/hip_runtime.h>
#include <math.h>

#define NTOK 1024
#define DIMM 512
#define NH 8
#define HD 64
#define BCB 16
#define BSB 16
#define KSEL 8
#define WWIN 256
#define CBLK 64
#define SCALE 0.125f
#define EPSV 1e-6f
#define NEGV -1e30f

typedef short bf16x8 __attribute__((ext_vector_type(8)));
typedef float f32x4 __attribute__((ext_vector_type(4)));

__device__ inline ushort f2b(float f) {
  union { float f; unsigned int u; } c; c.f = f;
  unsigned int u = c.u;
  return (ushort)((u + 0x7FFFu + ((u >> 16) & 1u)) >> 16);
}
__device__ inline float b2f(ushort h) {
  union { unsigned int u; float f; } c; c.u = ((unsigned int)h) << 16;
  return c.f;
}

__device__ inline float wred_max(float v) {
#pragma unroll
  for (int off = 1; off < 64; off <<= 1) v = fmaxf(v, __shfl_xor(v, off));
  return v;
}
__device__ inline float wred_sum(float v) {
#pragma unroll
  for (int off = 1; off < 64; off <<= 1) v += __shfl_xor(v, off);
  return v;
}

// ---------- residual mix + rmsnorm ----------
__global__ void __launch_bounds__(256)
k_resid_rms(const float* __restrict__ x, const float* __restrict__ x0,
            const float* __restrict__ lam, float* __restrict__ xr,
            float* __restrict__ xn) {
  int row = blockIdx.x, tid = threadIdx.x;
  float l0 = lam[0], l1 = lam[1];
  size_t b = (size_t)row * DIMM;
  float a0 = l0 * x[b + tid]       + l1 * x0[b + tid];
  float a1 = l0 * x[b + tid + 256] + l1 * x0[b + tid + 256];
  xr[b + tid] = a0; xr[b + tid + 256] = a1;
  float ss = a0 * a0 + a1 * a1;
  __shared__ float sm[8];
  for (int o = 32; o > 0; o >>= 1) ss += __shfl_down(ss, o);
  int lane = tid & 63, wid = tid >> 6;
  if (lane == 0) sm[wid] = ss;
  __syncthreads();
  if (tid == 0) {
    float s = sm[0] + sm[1] + sm[2] + sm[3];
    sm[0] = rsqrtf(s / (float)DIMM + EPSV);
  }
  __syncthreads();
  float r = sm[0];
  xn[b + tid] = a0 * r; xn[b + tid + 256] = a1 * r;
}

// ---------- fused Wo-combine + rmsnorm: x2 = xr+p0+p1 ; y = bf16(rms(x2)) ----------
__global__ void __launch_bounds__(256)
k_rms_bf(const float* __restrict__ xr, const float* __restrict__ p0,
         const float* __restrict__ p1, float* __restrict__ x2,
         ushort* __restrict__ y) {
  int row = blockIdx.x, tid = threadIdx.x;
  size_t b = (size_t)row * DIMM;
  float a0 = xr[b + tid]       + p0[b + tid]       + p1[b + tid];
  float a1 = xr[b + tid + 256] + p0[b + tid + 256] + p1[b + tid + 256];
  x2[b + tid] = a0; x2[b + tid + 256] = a1;
  float ss = a0 * a0 + a1 * a1;
  __shared__ float sm[8];
  for (int o = 32; o > 0; o >>= 1) ss += __shfl_down(ss, o);
  int lane = tid & 63, wid = tid >> 6;
  if (lane == 0) sm[wid] = ss;
  __syncthreads();
  if (tid == 0) {
    float s = sm[0] + sm[1] + sm[2] + sm[3];
    sm[0] = rsqrtf(s / (float)DIMM + EPSV);
  }
  __syncthreads();
  float r = sm[0];
  y[b + tid] = f2b(a0 * r); y[b + tid + 256] = f2b(a1 * r);
}

// ---------- consolidated weight transposes (f32 K×N -> bf16 hi/lo N×K) ----------
struct WtrDesc { const float* src; ushort* dh; ushort* dl; int K; int Nsrc; int Npad; };
struct WtrPack { WtrDesc d[9]; int cum[9]; };

__global__ void __launch_bounds__(256)
k_wtr_all(WtrPack pk) {
  int gb = blockIdx.x;
  int e = 0;
  while (gb >= pk.cum[e]) e++;
  int start = e ? pk.cum[e - 1] : 0;
  WtrDesc dd = pk.d[e];
  int local = gb - start;
  int XT = dd.Npad >> 5;
  int bx = local % XT, by = local / XT;
  __shared__ float t[32][33];
  int n0 = bx * 32, k0 = by * 32;
  int tx = threadIdx.x, ty = threadIdx.y;  // 32 x 8
#pragma unroll
  for (int i = 0; i < 32; i += 8)
    t[ty + i][tx] = (n0 + tx < dd.Nsrc)
        ? dd.src[(size_t)(k0 + ty + i) * dd.Nsrc + n0 + tx] : 0.f;
  __syncthreads();
#pragma unroll
  for (int i = 0; i < 32; i += 8) {
    float vv = t[tx][ty + i];
    ushort h = f2b(vv);
    size_t di = (size_t)(n0 + ty + i) * dd.K + k0 + tx;
    dd.dh[di] = h;
    if (dd.dl) dd.dl[di] = f2b(vv - b2f(h));
  }
}

// ---------- W1 GEMM: 128Mx64N tile, A bf16, relu^2 -> bf16. grid (32,8) ----------
__global__ void __launch_bounds__(256)
k_gemm_w1(const ushort* __restrict__ A, const ushort* __restrict__ BT,
          ushort* __restrict__ Co) {
  const int Kd = 512, Nd = 2048;
  __shared__ ushort As[128 * 40];
  __shared__ ushort Bs[64 * 40];
  int tid = threadIdx.x;
  int lane = tid & 63, w = tid >> 6;
  int rb = blockIdx.y * 128, cb = blockIdx.x * 64;
  int wm = (w >> 1) * 64, wn = (w & 1) * 32;
  int quad = lane >> 4, l15 = lane & 15;
  int srA = tid >> 1, scA = (tid & 1) * 16;
  int srB = tid >> 2, scB = (tid & 3) * 8;

  f32x4 acc[4][2];
#pragma unroll
  for (int i = 0; i < 4; i++)
#pragma unroll
    for (int j = 0; j < 2; j++) acc[i][j] = (f32x4){0.f, 0.f, 0.f, 0.f};

  const ushort* ap = A  + (size_t)(rb + srA) * Kd + scA;
  const ushort* bp = BT + (size_t)(cb + srB) * Kd + scB;
  ushort* aw = &As[srA * 40 + scA];
  ushort* bw = &Bs[srB * 40 + scB];

  int4 pa0 = *(const int4*)ap;
  int4 pa1 = *(const int4*)(ap + 8);
  int4 pb  = *(const int4*)bp;

  for (int k0 = 0; k0 < Kd; k0 += 32) {
    if (k0) __syncthreads();
    *(int4*)aw = pa0; *(int4*)(aw + 8) = pa1;
    *(int4*)bw = pb;
    __syncthreads();
    if (k0 + 32 < Kd) {
      pa0 = *(const int4*)(ap + k0 + 32);
      pa1 = *(const int4*)(ap + k0 + 40);
      pb  = *(const int4*)(bp + k0 + 32);
    }
    bf16x8 af[4], bfr[2];
#pragma unroll
    for (int t = 0; t < 4; t++)
      af[t] = *(const bf16x8*)&As[(wm + t * 16 + l15) * 40 + quad * 8];
#pragma unroll
    for (int t = 0; t < 2; t++)
      bfr[t] = *(const bf16x8*)&Bs[(wn + t * 16 + l15) * 40 + quad * 8];
#pragma unroll
    for (int i = 0; i < 4; i++)
#pragma unroll
      for (int j = 0; j < 2; j++)
        acc[i][j] = __builtin_amdgcn_mfma_f32_16x16x32_bf16(af[i], bfr[j],
                                                            acc[i][j], 0, 0, 0);
  }

#pragma unroll
  for (int i = 0; i < 4; i++) {
#pragma unroll
    for (int j = 0; j < 2; j++) {
      int col = cb + wn + j * 16 + l15;
#pragma unroll
      for (int r = 0; r < 4; r++) {
        int row = rb + wm + i * 16 + quad * 4 + r;
        float t = fmaxf(acc[i][j][r], 0.f);
        Co[(size_t)row * Nd + col] = f2b(t * t);
      }
    }
  }
}

// ---------- W2 GEMM: 64x64 tile, split-K, f32 partial out ----------
__global__ void __launch_bounds__(256)
k_gemm_w2(const ushort* __restrict__ A, const ushort* __restrict__ BT,
          float* __restrict__ P0, float* __restrict__ P1) {
  const int Kd = 2048;
  __shared__ ushort As[64 * 40];
  __shared__ ushort Bs[64 * 40];
  int tid = threadIdx.x;
  int lane = tid & 63, w = tid >> 6;
  int rb = blockIdx.y * 64, cb = blockIdx.x * 64;
  int kb = blockIdx.z * 1024;
  int wm = (w >> 1) * 32, wn = (w & 1) * 32;
  int quad = lane >> 4, l15 = lane & 15;
  int srow = tid >> 2, scol = (tid & 3) * 8;

  f32x4 acc[2][2];
#pragma unroll
  for (int i = 0; i < 2; i++)
#pragma unroll
    for (int j = 0; j < 2; j++) acc[i][j] = (f32x4){0.f, 0.f, 0.f, 0.f};

  const ushort* ap = A  + (size_t)(rb + srow) * Kd + kb + scol;
  const ushort* bp = BT + (size_t)(cb + srow) * Kd + kb + scol;
  ushort* aw = &As[srow * 40 + scol];
  ushort* bw = &Bs[srow * 40 + scol];

  int4 pa = *(const int4*)ap;
  int4 pb = *(const int4*)bp;

  for (int k0 = 0; k0 < 1024; k0 += 32) {
    if (k0) __syncthreads();
    *(int4*)aw = pa;
    *(int4*)bw = pb;
    __syncthreads();
    if (k0 + 32 < 1024) {
      pa = *(const int4*)(ap + k0 + 32);
      pb = *(const int4*)(bp + k0 + 32);
    }
    bf16x8 af[2], bfr[2];
#pragma unroll
    for (int t = 0; t < 2; t++) {
      af[t]  = *(const bf16x8*)&As[(wm + t * 16 + l15) * 40 + quad * 8];
      bfr[t] = *(const bf16x8*)&Bs[(wn + t * 16 + l15) * 40 + quad * 8];
    }
#pragma unroll
    for (int i = 0; i < 2; i++)
#pragma unroll
      for (int j = 0; j < 2; j++)
        acc[i][j] = __builtin_amdgcn_mfma_f32_16x16x32_bf16(af[i], bfr[j],
                                                            acc[i][j], 0, 0, 0);
  }

  float* pbuf = blockIdx.z ? P1 : P0;
#pragma unroll
  for (int i = 0; i < 2; i++) {
#pragma unroll
    for (int j = 0; j < 2; j++) {
      int col = cb + wn + j * 16 + l15;
#pragma unroll
      for (int r = 0; r < 4; r++) {
        int row = rb + wm + i * 16 + quad * 4 + r;
        pbuf[(size_t)row * 512 + col] = acc[i][j][r];
      }
    }
  }
}

// ---------- W2 finalize: out = x2 + p0 + p1 ----------
__global__ void __launch_bounds__(256)
k_w2fin(const float* __restrict__ x2, const float* __restrict__ p0,
        const float* __restrict__ p1, float* __restrict__ out) {
  int idx = blockIdx.x * 256 + threadIdx.x;
  out[idx] = x2[idx] + p0[idx] + p1[idx];
}

// ---------- Wo GEMM, split-K=2, fused gated combine in A-staging; partials out ----------
__global__ void __launch_bounds__(256)
k_gemm_wo(const float* __restrict__ cg, const float* __restrict__ fg,
          const float* __restrict__ sg, const float* __restrict__ gates,
          const ushort* __restrict__ BT, float* __restrict__ P0,
          float* __restrict__ P1) {
  __shared__ ushort As[64 * 40];
  __shared__ ushort Bs[64 * 40];
  int tid = threadIdx.x;
  int lane = tid & 63, wave = tid >> 6;
  int rb = blockIdx.y * 64, cb = blockIdx.x * 64;
  int kb = blockIdx.z * 256;
  int wm = (wave >> 1) * 32, wn = (wave & 1) * 32;
  int q = lane >> 4, l15 = lane & 15;
  int srow = tid >> 2, scol = (tid & 3) * 8;

  f32x4 acc[2][2];
#pragma unroll
  for (int i = 0; i < 2; i++)
#pragma unroll
    for (int j = 0; j < 2; j++) acc[i][j] = (f32x4){0.f, 0.f, 0.f, 0.f};

  int row = rb + srow;
  const ushort* bp = BT + (size_t)(cb + srow) * 512 + kb + scol;
  ushort* aw = &As[srow * 40 + scol];
  ushort* bw = &Bs[srow * 40 + scol];

  for (int k0 = 0; k0 < 256; k0 += 32) {
    int colb = kb + k0 + scol;
    int hh = colb >> 6;
    const float* gp = gates + (size_t)row * 24 + hh * 3;
    float g0 = gp[0], g1 = gp[1], g2 = gp[2];
    size_t off = (size_t)row * 512 + colb;
    float4 c0 = *(const float4*)(cg + off), c1 = *(const float4*)(cg + off + 4);
    float4 f0 = *(const float4*)(fg + off), f1 = *(const float4*)(fg + off + 4);
    float4 s0 = *(const float4*)(sg + off), s1 = *(const float4*)(sg + off + 4);
    float va[8] = {g0 * c0.x + g1 * f0.x + g2 * s0.x,
                   g0 * c0.y + g1 * f0.y + g2 * s0.y,
                   g0 * c0.z + g1 * f0.z + g2 * s0.z,
                   g0 * c0.w + g1 * f0.w + g2 * s0.w,
                   g0 * c1.x + g1 * f1.x + g2 * s1.x,
                   g0 * c1.y + g1 * f1.y + g2 * s1.y,
                   g0 * c1.z + g1 * f1.z + g2 * s1.z,
                   g0 * c1.w + g1 * f1.w + g2 * s1.w};
    ushort h[8];
#pragma unroll
    for (int e = 0; e < 8; e++) h[e] = f2b(va[e]);
    *(int4*)aw = *(int4*)h;
    *(int4*)bw = *(const int4*)(bp + k0);
    __syncthreads();
    bf16x8 af[2], bfr[2];
#pragma unroll
    for (int t = 0; t < 2; t++) {
      af[t]  = *(const bf16x8*)&As[(wm + t * 16 + l15) * 40 + q * 8];
      bfr[t] = *(const bf16x8*)&Bs[(wn + t * 16 + l15) * 40 + q * 8];
    }
#pragma unroll
    for (int i = 0; i < 2; i++)
#pragma unroll
      for (int j = 0; j < 2; j++)
        acc[i][j] = __builtin_amdgcn_mfma_f32_16x16x32_bf16(af[i], bfr[j],
                                                            acc[i][j], 0, 0, 0);
    __syncthreads();
  }

  float* pbuf = blockIdx.z ? P1 : P0;
#pragma unroll
  for (int i = 0; i < 2; i++) {
#pragma unroll
    for (int j = 0; j < 2; j++) {
      int col = cb + wn + j * 16 + l15;
#pragma unroll
      for (int r = 0; r < 4; r++) {
        int rr = rb + wm + i * 16 + q * 4 + r;
        pbuf[(size_t)rr * 512 + col] = acc[i][j][r];
      }
    }
  }
}

// ---------- split-bf16 MFMA GEMM: QKV + gates; hi/lo only for q/k columns ----------
__global__ void __launch_bounds__(256)
k_gemm_qkv(const float* __restrict__ A, const ushort* __restrict__ BTh,
           const ushort* __restrict__ BTl, float* __restrict__ Co,
           float* __restrict__ vhm, float* __restrict__ gates, int Kd) {
  __shared__ ushort Ash[64 * 40];
  __shared__ ushort Asl[64 * 40];
  __shared__ ushort Bsh[64 * 40];
  __shared__ ushort Bsl[64 * 40];
  int tid = threadIdx.x;
  int lane = tid & 63, wave = tid >> 6;
  int rb = blockIdx.y * 64, cb = blockIdx.x * 64;
  const bool prec = (cb < 1024);   // q/k columns need f32-grade (selection)
  int wm = (wave >> 1) * 32, wn = (wave & 1) * 32;
  int q = lane >> 4, l15 = lane & 15;
  int srow = tid >> 2, scol = (tid & 3) * 8;

  f32x4 acc[2][2];
#pragma unroll
  for (int i = 0; i < 2; i++)
#pragma unroll
    for (int j = 0; j < 2; j++) acc[i][j] = (f32x4){0.f, 0.f, 0.f, 0.f};

  const float*  ap  = A   + (size_t)(rb + srow) * Kd + scol;
  const ushort* bph = BTh + (size_t)(cb + srow) * Kd + scol;
  const ushort* bpl = BTl + (size_t)(cb + srow) * Kd + scol;
  ushort* awh = &Ash[srow * 40 + scol];
  ushort* awl = &Asl[srow * 40 + scol];
  ushort* bwh = &Bsh[srow * 40 + scol];
  ushort* bwl = &Bsl[srow * 40 + scol];

  for (int k0 = 0; k0 < Kd; k0 += 32) {
    float4 a0 = *(const float4*)(ap + k0);
    float4 a1 = *(const float4*)(ap + k0 + 4);
    float va[8] = {a0.x, a0.y, a0.z, a0.w, a1.x, a1.y, a1.z, a1.w};
    ushort hh[8], hl[8];
#pragma unroll
    for (int e = 0; e < 8; e++) hh[e] = f2b(va[e]);
    *(int4*)awh = *(int4*)hh;
    *(int4*)bwh = *(const int4*)(bph + k0);
    if (prec) {
#pragma unroll
      for (int e = 0; e < 8; e++) hl[e] = f2b(va[e] - b2f(hh[e]));
      *(int4*)awl = *(int4*)hl;
      *(int4*)bwl = *(const int4*)(bpl + k0);
    }
    __syncthreads();
    bf16x8 afh[2], afl[2], bfh[2], bfl[2];
#pragma unroll
    for (int t = 0; t < 2; t++) {
      int ar = (wm + t * 16 + l15) * 40 + q * 8;
      int br = (wn + t * 16 + l15) * 40 + q * 8;
      afh[t] = *(const bf16x8*)&Ash[ar];
      bfh[t] = *(const bf16x8*)&Bsh[br];
      if (prec) {
        afl[t] = *(const bf16x8*)&Asl[ar];
        bfl[t] = *(const bf16x8*)&Bsl[br];
      }
    }
#pragma unroll
    for (int i = 0; i < 2; i++)
#pragma unroll
      for (int j = 0; j < 2; j++) {
        acc[i][j] = __builtin_amdgcn_mfma_f32_16x16x32_bf16(afh[i], bfh[j],
                                                            acc[i][j], 0, 0, 0);
        if (prec) {
          acc[i][j] = __builtin_amdgcn_mfma_f32_16x16x32_bf16(afh[i], bfl[j],
                                                              acc[i][j], 0, 0, 0);
          acc[i][j] = __builtin_amdgcn_mfma_f32_16x16x32_bf16(afl[i], bfh[j],
                                                              acc[i][j], 0, 0, 0);
        }
      }
    __syncthreads();
  }

  const size_t NW = (size_t)NTOK * DIMM;
#pragma unroll
  for (int i = 0; i < 2; i++) {
#pragma unroll
    for (int j = 0; j < 2; j++) {
      int col = cb + wn + j * 16 + l15;
#pragma unroll
      for (int r = 0; r < 4; r++) {
        int row = rb + wm + i * 16 + q * 4 + r;
        float vv = acc[i][j][r];
        if (cb >= 1536) {
          int c24 = col - 1536;
          if (c24 < 24)
            gates[(size_t)row * 24 + c24] = 1.f / (1.f + expf(-vv));
        } else if (col >= 1024) {
          int c = col - 1024;   // v plane -> head-major
          vhm[(size_t)(c >> 6) * 65536 + (size_t)row * 64 + (c & 63)] = vv;
        } else {
          Co[(size_t)(col >> 9) * NW + (size_t)row * 512 + (col & 511)] = vv;
        }
      }
    }
  }
}

// ---------- RoPE: q in-place; k -> khm f32 + khm_bf bf16; vhm -> vhm_bf ----------
__global__ void __launch_bounds__(256)
k_rope(float* __restrict__ q, const float* __restrict__ k,
       float* __restrict__ khm, ushort* __restrict__ khm_bf,
       const float* __restrict__ vhm, ushort* __restrict__ vhm_bf) {
  int idx = blockIdx.x * 256 + threadIdx.x;
  int seg = idx >> 18;
  if (seg >= 2) {
    int ci = idx - 524288;
    if (ci < 131072) {
      float4 t = *(const float4*)(vhm + (size_t)ci * 4);
      ushort4 u = {f2b(t.x), f2b(t.y), f2b(t.z), f2b(t.w)};
      *(ushort4*)(vhm_bf + (size_t)ci * 4) = u;
    }
    return;
  }
  int r = idx & 262143;
  int j = r & 31;
  int h = (r >> 5) & 7;
  int n = r >> 8;
  float inv = powf(10000.f, -(float)j / 32.f);
  float ang = (float)n * inv;
  float sn, cs;
  sincosf(ang, &sn, &cs);
  size_t base = (size_t)n * DIMM + h * HD + j;
  if (seg == 0) {
    float x1 = q[base], x2 = q[base + 32];
    q[base] = x1 * cs - x2 * sn;
    q[base + 32] = x2 * cs + x1 * sn;
  } else {
    float x1 = k[base], x2 = k[base + 32];
    float o1 = x1 * cs - x2 * sn;
    float o2 = x2 * cs + x1 * sn;
    size_t ob = (size_t)h * 65536 + (size_t)n * 64 + j;
    khm[ob] = o1;
    khm[ob + 32] = o2;
    khm_bf[ob] = f2b(o1);
    khm_bf[ob + 32] = f2b(o2);
  }
}

// ---------- compressed k/v via MFMA hi/lo, M-split. grid (NH, 2 kv, 2 mh) ----------
__global__ void __launch_bounds__(256)
k_ckcv_m(const float* __restrict__ khm, const float* __restrict__ vhm,
         const float* __restrict__ k_pos, const float* __restrict__ v_pos,
         const ushort* __restrict__ WckTh, const ushort* __restrict__ WckTl,
         const ushort* __restrict__ WcvTh, const ushort* __restrict__ WcvTl,
         const float* __restrict__ bck, const float* __restrict__ bcv,
         float* __restrict__ ckb, float* __restrict__ cvb) {
  int h = blockIdx.x, kv = blockIdx.y, mh = blockIdx.z;
  const float* src = kv ? vhm : khm;
  const float* pos = kv ? v_pos : k_pos;
  const ushort* WTh = kv ? WcvTh : WckTh;
  const ushort* WTl = kv ? WcvTl : WckTl;
  const float* bias = kv ? bcv : bck;
  float* outp = kv ? cvb : ckb;

  __shared__ ushort Ash[32 * 72], Asl[32 * 72];
  __shared__ ushort Bsh[64 * 72], Bsl[64 * 72];
  int tid = threadIdx.x;
  int lane = tid & 63, wave = tid >> 6;
  int wmi = wave >> 1, wnj = wave & 1;
  int quad = lane >> 4, l15 = lane & 15;
  int arow = tid >> 3, ae0 = (tid & 7) * 8;   // A: 32 rows x 8 floats/thread
  int brow = tid >> 2, be0 = (tid & 3) * 16;  // B: 64 rows x 16/thread

  f32x4 acc[2];
#pragma unroll
  for (int j = 0; j < 2; j++) acc[j] = (f32x4){0.f, 0.f, 0.f, 0.f};

  for (int t = 0; t < 16; t++) {
    const float* ar = src + (size_t)h * 65536 +
                      (size_t)((mh * 32 + arow) * 16 + t) * 64 + ae0;
    const float* pr = pos + (size_t)(h * 16 + t) * HD + ae0;
    ushort hh[8], hl[8];
#pragma unroll
    for (int u = 0; u < 2; u++) {
      float4 av = *(const float4*)(ar + u * 4);
      float4 pv = *(const float4*)(pr + u * 4);
      float vals[4] = {av.x + pv.x, av.y + pv.y, av.z + pv.z, av.w + pv.w};
#pragma unroll
      for (int e = 0; e < 4; e++) {
        ushort hb = f2b(vals[e]);
        hh[u * 4 + e] = hb;
        hl[u * 4 + e] = f2b(vals[e] - b2f(hb));
      }
    }
    *(int4*)&Ash[arow * 72 + ae0] = *(int4*)hh;
    *(int4*)&Asl[arow * 72 + ae0] = *(int4*)hl;
    const ushort* bh = WTh + (size_t)brow * 1024 + t * 64 + be0;
    const ushort* bl = WTl + (size_t)brow * 1024 + t * 64 + be0;
    *(int4*)&Bsh[brow * 72 + be0]     = *(const int4*)bh;
    *(int4*)&Bsh[brow * 72 + be0 + 8] = *(const int4*)(bh + 8);
    *(int4*)&Bsl[brow * 72 + be0]     = *(const int4*)bl;
    *(int4*)&Bsl[brow * 72 + be0 + 8] = *(const int4*)(bl + 8);
    __syncthreads();
#pragma unroll
    for (int sub = 0; sub < 2; sub++) {
      int ar2 = (wmi * 16 + l15) * 72 + sub * 32 + quad * 8;
      bf16x8 afh = *(const bf16x8*)&Ash[ar2];
      bf16x8 afl = *(const bf16x8*)&Asl[ar2];
#pragma unroll
      for (int j = 0; j < 2; j++) {
        int br2 = (wnj * 32 + j * 16 + l15) * 72 + sub * 32 + quad * 8;
        bf16x8 bfh = *(const bf16x8*)&Bsh[br2];
        bf16x8 bfl = *(const bf16x8*)&Bsl[br2];
        acc[j] = __builtin_amdgcn_mfma_f32_16x16x32_bf16(afh, bfh, acc[j], 0, 0, 0);
        acc[j] = __builtin_amdgcn_mfma_f32_16x16x32_bf16(afh, bfl, acc[j], 0, 0, 0);
        acc[j] = __builtin_amdgcn_mfma_f32_16x16x32_bf16(afl, bfh, acc[j], 0, 0, 0);
      }
    }
    __syncthreads();
  }

#pragma unroll
  for (int j = 0; j < 2; j++) {
    int d = wnj * 32 + j * 16 + l15;
    float bv = bias[d];
#pragma unroll
    for (int r = 0; r < 4; r++) {
      int c = mh * 32 + wmi * 16 + quad * 4 + r;
      outp[((size_t)h * 64 + c) * 64 + d] = acc[j][r] + bv;
    }
  }
}

// ---------- compressed attention + top-8 (f32 path — selection-critical) ----------
__global__ void __launch_bounds__(256)
k_cmp(const float* __restrict__ qg, const float* __restrict__ ckb,
      const float* __restrict__ cvb, const float* __restrict__ k_mem,
      const float* __restrict__ v_mem, float* __restrict__ cout,
      int* __restrict__ sel) {
  int h = blockIdx.y, i0 = blockIdx.x * 16;
  int tid = threadIdx.x, lane = tid & 63, w = tid >> 6;
  __shared__ float ckt[64][65];
  __shared__ float cvs[64][65];
  __shared__ float qs[16][64];
  __shared__ float kms[64], vms[64];
  __shared__ float sp[4][64];

#pragma unroll
  for (int r = 0; r < 4; r++) {
    int f = r * 256 + tid;
    int c = f >> 4, d0 = (f & 15) * 4;
    float4 t = *(const float4*)(ckb + ((size_t)h * 64 + c) * 64 + d0);
    ckt[d0][c] = t.x; ckt[d0 + 1][c] = t.y; ckt[d0 + 2][c] = t.z; ckt[d0 + 3][c] = t.w;
    float4 u = *(const float4*)(cvb + ((size_t)h * 64 + c) * 64 + d0);
    cvs[c][d0] = u.x; cvs[c][d0 + 1] = u.y; cvs[c][d0 + 2] = u.z; cvs[c][d0 + 3] = u.w;
  }
  {
    int r = tid >> 4, d0 = (tid & 15) * 4;
    float4 t = *(const float4*)(qg + (size_t)(i0 + r) * DIMM + h * HD + d0);
    qs[r][d0] = t.x; qs[r][d0 + 1] = t.y; qs[r][d0 + 2] = t.z; qs[r][d0 + 3] = t.w;
  }
  if (tid < 64) kms[tid] = k_mem[h * HD + tid];
  else if (tid < 128) vms[tid - 64] = v_mem[h * HD + tid - 64];
  __syncthreads();

  for (int s = 0; s < 4; s++) {
    int ql = w * 4 + s, qi = i0 + ql;
    float dot = 0.f, dm = 0.f;
#pragma unroll 8
    for (int e = 0; e < 64; e++) {
      float qe = qs[ql][e];
      dot = fmaf(qe, ckt[e][lane], dot);
      dm  = fmaf(qe, kms[e], dm);
    }
    bool vis = (lane * BCB + BCB - 1) < qi;
    float sj = vis ? dot * SCALE : NEGV;
    float smem = dm * SCALE;
    float m = wred_max(fmaxf(sj, smem));
    float p = expf(sj - m);
    float pmem = expf(smem - m);
    float l = wred_sum(p) + pmem;
    float inv = 1.f / l;

    float impv = vis ? p : NEGV;
#pragma unroll
    for (int kk = 0; kk < KSEL; kk++) {
      float bv = impv; int bi = lane;
#pragma unroll
      for (int off = 32; off > 0; off >>= 1) {
        float ov = __shfl_xor(bv, off);
        int   oi = __shfl_xor(bi, off);
        if (ov > bv || (ov == bv && oi < bi)) { bv = ov; bi = oi; }
      }
      if (lane == 0) sel[((size_t)h * NTOK + qi) * KSEL + kk] = (bv >= 0.f) ? bi : -1;
      if (lane == bi) impv = NEGV;
    }

    sp[w][lane] = p;
    float od = pmem * vms[lane];
#pragma unroll 8
    for (int j = 0; j < 64; j++) od = fmaf(sp[w][j], cvs[j][lane], od);
    cout[(size_t)qi * DIMM + h * HD + lane] = od * inv;
  }
}

// ---------- sliding window: MFMA flash, 32 q-rows / 128 threads. grid (32, NH) ----------
__global__ void __launch_bounds__(128)
k_swin(const float* __restrict__ qg, const ushort* __restrict__ khm_bf,
       const ushort* __restrict__ vhm_bf, float* __restrict__ sout) {
  int h = blockIdx.y, i0 = blockIdx.x * 32;
  int tid = threadIdx.x, lane = tid & 63, w = tid >> 6;   // w in {0,1}
  int quad = lane >> 4, l15 = lane & 15;

  __shared__ ushort Kt[64 * 72];
  __shared__ ushort VT[64 * 72];
  __shared__ ushort Qs[32 * 72];
  __shared__ ushort Ps[2][16 * 72];

#pragma unroll
  for (int it = 0; it < 2; it++) {
    int f = it * 128 + tid;            // 256 chunks of 8 ushorts (32 rows)
    int r = f >> 3, d0 = (f & 7) * 8;
    const float* qp = qg + (size_t)(i0 + r) * DIMM + h * HD + d0;
    float4 t0 = *(const float4*)qp;
    float4 t1 = *(const float4*)(qp + 4);
    ushort u[8] = {f2b(t0.x), f2b(t0.y), f2b(t0.z), f2b(t0.w),
                   f2b(t1.x), f2b(t1.y), f2b(t1.z), f2b(t1.w)};
    *(int4*)&Qs[r * 72 + d0] = *(int4*)u;
  }

  int lo = i0 - (WWIN - 1); if (lo < 0) lo = 0;
  int jb_lo = lo >> 6, jb_hi = (i0 + 31) >> 6;

  float mrow[4], lrow[4];
  f32x4 Of[4];
#pragma unroll
  for (int r = 0; r < 4; r++) { mrow[r] = NEGV; lrow[r] = 0.f; }
#pragma unroll
  for (int d = 0; d < 4; d++) Of[d] = (f32x4){0.f, 0.f, 0.f, 0.f};

  for (int jb = jb_lo; jb <= jb_hi; jb++) {
    __syncthreads();
#pragma unroll
    for (int it = 0; it < 4; it++) {
      int f = it * 128 + tid;          // 512 chunks (64 rows)
      int r = f >> 3, c8 = (f & 7) * 8;
      const ushort* kp = khm_bf + (size_t)h * 65536 + (size_t)(jb * 64 + r) * 64 + c8;
      *(int4*)&Kt[r * 72 + c8] = *(const int4*)kp;
      const ushort* vp = vhm_bf + (size_t)h * 65536 + (size_t)(jb * 64 + r) * 64 + c8;
      ushort vv[8];
      *(int4*)vv = *(const int4*)vp;
#pragma unroll
      for (int e = 0; e < 8; e++) VT[(c8 + e) * 72 + r] = vv[e];
    }
    __syncthreads();

    bf16x8 qa[2];
#pragma unroll
    for (int c = 0; c < 2; c++)
      qa[c] = *(const bf16x8*)&Qs[(w * 16 + l15) * 72 + c * 32 + quad * 8];

    f32x4 sc[4];
#pragma unroll
    for (int ks = 0; ks < 4; ks++) {
      f32x4 a = (f32x4){0.f, 0.f, 0.f, 0.f};
#pragma unroll
      for (int c = 0; c < 2; c++) {
        bf16x8 kb = *(const bf16x8*)&Kt[(ks * 16 + l15) * 72 + c * 32 + quad * 8];
        a = __builtin_amdgcn_mfma_f32_16x16x32_bf16(qa[c], kb, a, 0, 0, 0);
      }
      sc[ks] = a;
    }

    float pm[4][4], rmax[4];
#pragma unroll
    for (int r = 0; r < 4; r++) rmax[r] = NEGV;
#pragma unroll
    for (int ks = 0; ks < 4; ks++) {
      int gj = jb * 64 + ks * 16 + l15;
#pragma unroll
      for (int r = 0; r < 4; r++) {
        int qi = i0 + w * 16 + quad * 4 + r;
        bool vis = (gj <= qi) && (qi - gj < WWIN);
        float s = vis ? sc[ks][r] * SCALE : NEGV;
        pm[ks][r] = s;
        rmax[r] = fmaxf(rmax[r], s);
      }
    }
#pragma unroll
    for (int off = 1; off < 16; off <<= 1)
#pragma unroll
      for (int r = 0; r < 4; r++)
        rmax[r] = fmaxf(rmax[r], __shfl_xor(rmax[r], off));

    float alpha[4], rsum[4];
#pragma unroll
    for (int r = 0; r < 4; r++) {
      float newm = fmaxf(mrow[r], rmax[r]);
      alpha[r] = expf(mrow[r] - newm);
      mrow[r] = newm;
      rsum[r] = 0.f;
    }
#pragma unroll
    for (int ks = 0; ks < 4; ks++)
#pragma unroll
      for (int r = 0; r < 4; r++) {
        float p = expf(pm[ks][r] - mrow[r]);
        pm[ks][r] = p;
        rsum[r] += p;
      }
#pragma unroll
    for (int off = 1; off < 16; off <<= 1)
#pragma unroll
      for (int r = 0; r < 4; r++)
        rsum[r] += __shfl_xor(rsum[r], off);
#pragma unroll
    for (int r = 0; r < 4; r++)
      lrow[r] = lrow[r] * alpha[r] + rsum[r];

#pragma unroll
    for (int ks = 0; ks < 4; ks++)
#pragma unroll
      for (int r = 0; r < 4; r++)
        Ps[w][(quad * 4 + r) * 72 + ks * 16 + l15] = f2b(pm[ks][r]);
#pragma unroll
    for (int d = 0; d < 4; d++)
#pragma unroll
      for (int r = 0; r < 4; r++)
        Of[d][r] *= alpha[r];

#pragma unroll
    for (int c = 0; c < 2; c++) {
      bf16x8 pa = *(const bf16x8*)&Ps[w][l15 * 72 + c * 32 + quad * 8];
#pragma unroll
      for (int d = 0; d < 4; d++) {
        bf16x8 vb = *(const bf16x8*)&VT[(d * 16 + l15) * 72 + c * 32 + quad * 8];
        Of[d] = __builtin_amdgcn_mfma_f32_16x16x32_bf16(pa, vb, Of[d], 0, 0, 0);
      }
    }
  }

#pragma unroll
  for (int d = 0; d < 4; d++)
#pragma unroll
    for (int r = 0; r < 4; r++) {
      int qi = i0 + w * 16 + quad * 4 + r;
      sout[(size_t)qi * DIMM + h * HD + d * 16 + l15] = Of[d][r] / lrow[r];
    }
}

// ---------- fine attention: bf16 K/V mirrors ----------
__global__ void __launch_bounds__(256)
k_fine(const float* __restrict__ qg, const ushort* __restrict__ khm_bf,
       const ushort* __restrict__ vhm_bf, const int* __restrict__ sel,
       float* __restrict__ fout) {
  int i = blockIdx.x, h = blockIdx.y;
  int tid = threadIdx.x, lane = tid & 63, w = tid >> 6;
  __shared__ float qsh[64];
  __shared__ ushort vsb[144 * 64];
  __shared__ float sp[144];
  __shared__ int selS[8];
  __shared__ float mred[4], sredS[4];
  __shared__ float pacc[4][64];

  int own = i >> 4;
  if (tid < 64) qsh[tid] = qg[(size_t)i * DIMM + h * HD + tid];
  if (tid >= 64 && tid < 72)
    selS[tid - 64] = sel[((size_t)h * NTOK + i) * KSEL + tid - 64];
  __syncthreads();

  const ushort* kbase = khm_bf + (size_t)h * 65536;
  const ushort* vbase = vhm_bf + (size_t)h * 65536;

#pragma unroll
  for (int it = 0; it < 5; it++) {
    int idx = it * 256 + tid;
    if (idx < 1152) {
      int row = idx >> 3, c8 = (idx & 7) * 8;
      int kk = row >> 4;
      int bidx = (kk < KSEL) ? selS[kk] : own;
      if (bidx < 0) bidx = 0;
      *(int4*)&vsb[row * 64 + c8] =
          *(const int4*)(vbase + (size_t)(bidx * BSB + (row & 15)) * 64 + c8);
    }
  }

  float s_loc = NEGV;
  bool active = (tid < 144);
  if (active) {
    int kk = tid >> 4;
    int bidx; bool vis;
    if (kk < KSEL) {
      bidx = selS[kk];
      vis = (bidx >= 0);
      if (!vis) bidx = 0;
    } else {
      bidx = own;
      vis = (tid - 128) <= (i & 15);
    }
    const ushort* kr = kbase + (size_t)(bidx * BSB + (tid & 15)) * 64;
    float dot = 0.f;
#pragma unroll
    for (int e8 = 0; e8 < 8; e8++) {
      ushort kv[8];
      *(int4*)kv = *(const int4*)(kr + e8 * 8);
#pragma unroll
      for (int e = 0; e < 8; e++)
        dot = fmaf(qsh[e8 * 8 + e], b2f(kv[e]), dot);
    }
    s_loc = vis ? dot * SCALE : NEGV;
  }
  float mw = wred_max(s_loc);
  if (lane == 0) mred[w] = mw;
  __syncthreads();
  float m = fmaxf(fmaxf(mred[0], mred[1]), fmaxf(mred[2], mred[3]));
  float p = active ? expf(s_loc - m) : 0.f;
  float sw = wred_sum(p);
  if (lane == 0) sredS[w] = sw;
  if (active) sp[tid] = p;
  __syncthreads();
  float l = sredS[0] + sredS[1] + sredS[2] + sredS[3];

  float acc = 0.f;
  int j0 = w * 36;
#pragma unroll 6
  for (int jj = 0; jj < 36; jj++) {
    int j = j0 + jj;
    acc = fmaf(sp[j], b2f(vsb[j * 64 + lane]), acc);
  }
  pacc[w][lane] = acc;
  __syncthreads();
  if (w == 0)
    fout[(size_t)i * DIMM + h * HD + lane] =
        (pacc[0][lane] + pacc[1][lane] + pacc[2][lane] + pacc[3][lane]) / l;
}

extern "C" void kernel_launch(void* const* d_in, const int* in_sizes, int n_in,
                              void* d_out, int out_size, void* d_ws, size_t ws_size,
                              hipStream_t stream) {
  const float* x     = (const float*)d_in[0];
  const float* ve    = (const float*)d_in[1]; (void)ve;
  const float* x0    = (const float*)d_in[2];
  const float* lam   = (const float*)d_in[3];
  const float* Wq    = (const float*)d_in[4];
  const float* Wk    = (const float*)d_in[5];
  const float* Wv    = (const float*)d_in[6];
  const float* Wo    = (const float*)d_in[7];
  const float* Wg    = (const float*)d_in[8];
  const float* k_pos = (const float*)d_in[9];
  const float* v_pos = (const float*)d_in[10];
  const float* Wck   = (const float*)d_in[11];
  const float* bck   = (const float*)d_in[12];
  const float* Wcv   = (const float*)d_in[13];
  const float* bcv   = (const float*)d_in[14];
  const float* k_mem = (const float*)d_in[15];
  const float* v_mem = (const float*)d_in[16];
  const float* W1    = (const float*)d_in[17];
  const float* W2    = (const float*)d_in[18];
  float* out = (float*)d_out;
  float* ws  = (float*)d_ws;

  const size_t NW = (size_t)NTOK * DIMM;   // 524288
  float* xr    = ws;              // f32 residual (read through rms_bf)
  float* xn    = ws + 1 * NW;     // after qkv: khm_bf+vhm_bf mirrors; later W2 p0
  float* q     = ws + 2 * NW;     // later: Wo partial p1w, then h1b
  float* k     = ws + 3 * NW;     // later: Wo partial p0w, then h1b (upper)
  float* vhm   = ws + 4 * NW;     // head-major v f32; later W2 p1
  float* coutb = ws + 5 * NW;
  float* foutb = ws + 6 * NW;
  float* soutb = ws + 7 * NW;     // later: ybf (bf16 overlay)
  float* x2    = ws + 8 * NW;     // khm f32 until rms_bf overwrites as x2
  float* khm   = x2;
  float* gates = ws + 9 * NW;
  float* ckb   = gates + 32768;
  float* cvb   = ckb + 32768;
  int*   selb  = (int*)(cvb + 32768);
  ushort* qkvTh = (ushort*)(cvb + 32768 + 65536);
  ushort* qkvTl = qkvTh + 1600 * 512;
  ushort* WoT   = qkvTl + 1600 * 512;
  ushort* W1T   = WoT   + 512 * 512;
  ushort* W2T   = W1T   + 2048 * 512;
  ushort* WckTh = W2T   + 512 * 2048;
  ushort* WckTl = WckTh + 64 * 1024;
  ushort* WcvTh = WckTl + 64 * 1024;
  ushort* WcvTl = WcvTh + 64 * 1024;
  float* p0w = k;                 // Wo split-K partials (k, q slots dead)
  float* p1w = q;
  ushort* ybf = (ushort*)soutb;   // bf16 y (soutb dead after wo)
  ushort* h1b = (ushort*)q;       // bf16 h1 (slots 2-3, after rms_bf read p's)
  float* p0 = xn;                 // W2 split-K partials
  float* p1 = vhm;
  ushort* khm_bf = (ushort*)xn;   // 1 MB (xn dead after qkv)
  ushort* vhm_bf = khm_bf + 524288;

  WtrPack pk;
  pk.d[0] = {Wq, qkvTh,              qkvTl,              512, 512,  512};
  pk.d[1] = {Wk, qkvTh + 512 * 512,  qkvTl + 512 * 512,  512, 512,  512};
  pk.d[2] = {Wv, qkvTh + 1024 * 512, qkvTl + 1024 * 512, 512, 512,  512};
  pk.d[3] = {Wo, WoT, nullptr,  512, 512,  512};
  pk.d[4] = {W1, W1T, nullptr,  512, 2048, 2048};
  pk.d[5] = {W2, W2T, nullptr, 2048, 512,  512};
  pk.d[6] = {Wck, WckTh, WckTl, 1024, 64, 64};
  pk.d[7] = {Wcv, WcvTh, WcvTl, 1024, 64, 64};
  pk.d[8] = {Wg, qkvTh + 1536 * 512, qkvTl + 1536 * 512, 512, 24, 64};
  int cum = 0;
  for (int e = 0; e < 9; e++) {
    cum += (pk.d[e].Npad / 32) * (pk.d[e].K / 32);
    pk.cum[e] = cum;
  }
  k_wtr_all<<<cum, dim3(32, 8), 0, stream>>>(pk);

  k_resid_rms<<<NTOK, 256, 0, stream>>>(x, x0, lam, xr, xn);

  k_gemm_qkv<<<dim3(25, NTOK / 64), 256, 0, stream>>>(
      xn, qkvTh, qkvTl, q, vhm, gates, 512);
  k_rope<<<2560, 256, 0, stream>>>(q, k, khm, khm_bf, vhm, vhm_bf);

  k_ckcv_m<<<dim3(NH, 2, 2), 256, 0, stream>>>(khm, vhm, k_pos, v_pos,
                                               WckTh, WckTl, WcvTh, WcvTl,
                                               bck, bcv, ckb, cvb);
  k_cmp<<<dim3(NTOK / 16, NH), 256, 0, stream>>>(q, ckb, cvb, k_mem, v_mem,
                                                 coutb, selb);
  k_swin<<<dim3(NTOK / 32, NH), 128, 0, stream>>>(q, khm_bf, vhm_bf, soutb);
  k_fine<<<dim3(NTOK, NH), 256, 0, stream>>>(q, khm_bf, vhm_bf, selb, foutb);

  // Wo split-K=2 -> 256 blocks; combine folded into rms_bf
  k_gemm_wo<<<dim3(512 / 64, NTOK / 64, 2), 256, 0, stream>>>(
      coutb, foutb, soutb, gates, WoT, p0w, p1w);
  k_rms_bf<<<NTOK, 256, 0, stream>>>(xr, p0w, p1w, x2, ybf);

  k_gemm_w1<<<dim3(2048 / 64, NTOK / 128), 256, 0, stream>>>(ybf, W1T, h1b);
  k_gemm_w2<<<dim3(512 / 64, NTOK / 64, 2), 256, 0, stream>>>(h1b, W2T, p0, p1);
  k_w2fin<<<NW / 256, 256, 0, stream>>>(x2, p0, p1, out);
}